// Round 11
// baseline (459.676 us; speedup 1.0000x reference)
//
#include <hip/hip_runtime.h>
#include <hip/hip_bf16.h>
#include <hip/hip_cooperative_groups.h>
#include <math.h>

#define NB 4
#define LIN 40960
#define NC 512
#define T0 8192
#define T1 2048
#define T2 1024
#define T3 512
#define TN 256
#define DM 2048
#define EPSF 1e-5f
#define TEMPF 1e-5f

typedef __attribute__((ext_vector_type(8))) short bf16x8;
typedef __attribute__((ext_vector_type(4))) float f32x4;

__device__ __forceinline__ int refl(int t, int T) {
  if (t < 0) t = -t;
  if (t >= T) t = 2 * T - 2 - t;
  return t;
}

__device__ __forceinline__ void gld16(void* lds, const void* g) {
  __builtin_amdgcn_global_load_lds((const __attribute__((address_space(1))) unsigned int*)g,
                                   (__attribute__((address_space(3))) unsigned int*)lds, 16, 0, 0);
}

__device__ __forceinline__ void blk_sum2_512(float& a, float& b, float* scratch) {
#pragma unroll
  for (int off = 32; off > 0; off >>= 1) {
    a += __shfl_down(a, off, 64);
    b += __shfl_down(b, off, 64);
  }
  int lane = threadIdx.x & 63, wid = threadIdx.x >> 6;
  __syncthreads();
  if (lane == 0) { scratch[wid] = a; scratch[8 + wid] = b; }
  __syncthreads();
  float sa = 0.f, sb = 0.f;
#pragma unroll
  for (int i = 0; i < 8; i++) { sa += scratch[i]; sb += scratch[8 + i]; }
  a = sa; b = sb;
}

__device__ __forceinline__ void add_bf8(const __hip_bfloat16* p, float* v) {
  union { uint4 u; __hip_bfloat16 h[8]; } pk;
  pk.u = *(const uint4*)p;
#pragma unroll
  for (int j = 0; j < 8; j++) v[j] += __bfloat162float(pk.h[j]);
}

// ---------------- merged init: conv0 (blocks 0..4095) + weight prep ----------------
template <int KT>
__device__ __forceinline__ void prep_conv_body(const float* __restrict__ w, __hip_bfloat16* __restrict__ wt,
                                               int co, float* l) {
  const float* wb = w + (size_t)co * 512 * KT;
  for (int i = threadIdx.x; i < 512 * KT; i += 512) l[i] = wb[i];
  __syncthreads();
  __hip_bfloat16* wo = wt + (size_t)co * 512 * KT;
  for (int i = threadIdx.x; i < 512 * KT; i += 512) {
    int kk = i >> 9, ci = i & 511;
    wo[i] = __float2bfloat16(l[ci * KT + kk]);
  }
}

template <int KD, int ND>
__device__ __forceinline__ void prep_mlp_body(const float* __restrict__ w, __hip_bfloat16* __restrict__ wt,
                                              int bidx, float* sbuf) {
  float(*tile)[33] = (float(*)[33])sbuf;
  int bx = bidx % (ND / 32);
  int by = bidx / (ND / 32);
  int tx = threadIdx.x & 31, ty = threadIdx.x >> 5;  // ty 0..15
#pragma unroll
  for (int i = 0; i < 32; i += 16)
    tile[ty + i][tx] = w[(size_t)(by * 32 + ty + i) * ND + bx * 32 + tx];
  __syncthreads();
#pragma unroll
  for (int i = 0; i < 32; i += 16)
    wt[(size_t)(bx * 32 + ty + i) * KD + by * 32 + tx] = __float2bfloat16(tile[tx][ty + i]);
}

__device__ __forceinline__ void conv0_body(const float* __restrict__ x, const float* __restrict__ w,
                                           const float* __restrict__ bias, const float* __restrict__ gw,
                                           const float* __restrict__ gb, __hip_bfloat16* __restrict__ out,
                                           int blk, float* smem) {
  float* xv = smem;
  float* tb = smem + 64;
  float* stats = smem + 4672;
  int b = blk / (T0 / 8);
  int t0 = (blk % (T0 / 8)) * 8;
  int tid = threadIdx.x;
  if (tid < 45) xv[tid] = x[(size_t)b * LIN + refl(t0 * 5 - 3 + tid, LIN)];
  __syncthreads();
  float wk[10];
#pragma unroll
  for (int k = 0; k < 10; k++) wk[k] = w[tid * 10 + k];
  float bs = bias[tid];
  float acc[8];
#pragma unroll
  for (int tt = 0; tt < 8; tt++) {
    float a = bs;
#pragma unroll
    for (int k = 0; k < 10; k++) a += xv[tt * 5 + k] * wk[k];
    acc[tt] = a;
    tb[tid * 9 + tt] = a;
  }
  __syncthreads();
  int wave = tid >> 6, lane = tid & 63;
  float s = 0.f, q = 0.f;
#pragma unroll
  for (int j = 0; j < 8; j++) {
    float v = tb[(lane * 8 + j) * 9 + wave];
    s += v; q += v * v;
  }
#pragma unroll
  for (int off = 32; off > 0; off >>= 1) {
    s += __shfl_xor(s, off, 64);
    q += __shfl_xor(q, off, 64);
  }
  if (lane == 0) {
    float mean = s * (1.f / NC);
    float var = fmaxf((q - s * s * (1.f / NC)) * (1.f / (NC - 1)), 0.f);
    stats[wave] = mean;
    stats[8 + wave] = rsqrtf(var + EPSF);
  }
  __syncthreads();
  float gwv = gw[tid], gbv = gb[tid];
#pragma unroll
  for (int tt = 0; tt < 8; tt++) {
    float y = (acc[tt] - stats[tt]) * stats[8 + tt] * gwv + gbv;
    out[((size_t)(b * T0 + t0 + tt)) * NC + tid] = __float2bfloat16(fmaxf(y, 0.f));
  }
}

__global__ __launch_bounds__(512) void k_init(const float* x, const float* c0w, const float* c0b,
                                              const float* n0w, const float* n0b, __hip_bfloat16* h0b,
                                              const float* c1w, const float* c2w, const float* c3w,
                                              const float* mw1, const float* mw2,
                                              __hip_bfloat16* wt1, __hip_bfloat16* wt2,
                                              __hip_bfloat16* wt3, __hip_bfloat16* wm1t,
                                              __hip_bfloat16* wm2t) {
  __shared__ float smem[4688];
  int b = blockIdx.x;
  if (b < 4096) conv0_body(x, c0w, c0b, n0w, n0b, h0b, b, smem);
  else if (b < 4608) prep_conv_body<8>(c1w, wt1, b - 4096, smem);
  else if (b < 5120) prep_conv_body<4>(c2w, wt2, b - 4608, smem);
  else if (b < 5632) prep_conv_body<4>(c3w, wt3, b - 5120, smem);
  else if (b < 6656) prep_mlp_body<512, 2048>(mw1, wm1t, b - 5632, smem);
  else prep_mlp_body<2048, 2048>(mw2, wm2t, b - 6656, smem);
}

// ---------------- GEMM B: 128x128 tile (wave=64x64), BK=32, A dbuf + B chunk-dbuf (64K),
// SK, strength-reduced. 3 blocks/CU (LDS 48KB). The measured-best-total config (315.1us).
template <int MODE, int TIN_, int TOUT_, int SS, int PP, int KK, int NN, int SPLITK, int MM>
__global__ __launch_bounds__(256) void k_gemmB(const __hip_bfloat16* __restrict__ A,
                                               const __hip_bfloat16* __restrict__ Bt,
                                               __hip_bfloat16* __restrict__ Cp) {
  __shared__ __align__(16) __hip_bfloat16 sA[2][128 * 32];
  __shared__ __align__(16) __hip_bfloat16 sB[2][2][128 * 32];  // [chunk-buf][sub][...]
  const int tid = threadIdx.x;
  const int lane = tid & 63;
  const int wave = tid >> 6;
  const int wm = wave >> 1, wn = wave & 1;
  constexpr int nt = NN / 128;
  constexpr int PS = (MM / 1024) * nt;
  constexpr int KBT = KK / 32;
  const int blk = blockIdx.x;
  const int xs = blk & 7, sl = blk >> 3;
  const int sk = sl / PS, rem = sl % PS;
  const int row0 = ((rem / nt) * 8 + xs) * 128;
  const int col0 = (rem % nt) * 128;
  const int kb0 = (sk * KBT) / SPLITK, kb1 = ((sk + 1) * KBT) / SPLITK;
  const int cq = lane >> 4, cl = lane & 15;

  const char* aP[2];
  const char* bP[2];

  auto stageA = [&](int kb, int buf) {
    bool recalc = (kb == kb0) || (MODE == 1 && (kb & 15) == 0);
    if (recalc) {
#pragma unroll
      for (int rr = 0; rr < 2; rr++) {
        int c = rr * 256 + tid;
        int m = c >> 2, kc = c & 3;
        int kcs = kc ^ (m & 3);
        size_t ga;
        if (MODE == 0) {
          ga = (size_t)(row0 + m) * KK + kb * 32 + kcs * 8;
        } else {
          int r = row0 + m;
          int bb = r / TOUT_;
          int t = r - bb * TOUT_;
          int k = (kb * 32) >> 9;
          int ci = ((kb * 32) & 511) + kcs * 8;
          int gt = refl(t * SS - PP + k, TIN_);
          ga = (((size_t)(bb * TIN_ + gt)) << 9) + ci;
        }
        aP[rr] = (const char*)(A + ga);
      }
    }
#pragma unroll
    for (int rr = 0; rr < 2; rr++) {
      gld16((char*)&sA[buf][0] + (rr * 256 + tid) * 16, aP[rr]);
      aP[rr] += 64;
    }
  };

  // Stages a full 64-K chunk (2 sub-tiles) into chunk-buf `buf`; advances bP by 128B.
  auto stageB = [&](int buf, bool doSub1) {
#pragma unroll
    for (int rr = 0; rr < 2; rr++) {
      gld16((char*)&sB[buf][0][0] + (rr * 256 + tid) * 16, bP[rr]);
      if (doSub1) gld16((char*)&sB[buf][1][0] + (rr * 256 + tid) * 16, bP[rr] + 64);
      bP[rr] += 128;
    }
  };

#pragma unroll
  for (int rr = 0; rr < 2; rr++) {
    int c = rr * 256 + tid;
    int n = c >> 2, kc = c & 3;
    int kcs = kc ^ (n & 3);
    bP[rr] = (const char*)(Bt + (size_t)(col0 + n) * KK + kb0 * 32 + kcs * 8);
  }

  f32x4 acc[4][4];
  const f32x4 zz = {0.f, 0.f, 0.f, 0.f};
#pragma unroll
  for (int mi = 0; mi < 4; mi++)
#pragma unroll
    for (int ni = 0; ni < 4; ni++) acc[mi][ni] = zz;

  stageA(kb0, 0);
  stageB(0, kb0 + 1 < kb1);

  const int p = cq ^ (cl & 3);
  for (int kb = kb0; kb < kb1; kb++) {
    const int jj = kb - kb0;
    __syncthreads();
    if (kb + 1 < kb1) stageA(kb + 1, (jj + 1) & 1);
    if (((jj & 1) == 0) && (kb + 2 < kb1)) stageB(((jj >> 1) + 1) & 1, kb + 3 < kb1);
    const short* bA = (const short*)&sA[jj & 1][0];
    const short* bB = (const short*)&sB[(jj >> 1) & 1][jj & 1][0];
    bf16x8 af[4], bfr[4];
#pragma unroll
    for (int mi = 0; mi < 4; mi++)
      af[mi] = *(const bf16x8*)(bA + (wm * 64 + mi * 16 + cl) * 32 + p * 8);
#pragma unroll
    for (int ni = 0; ni < 4; ni++)
      bfr[ni] = *(const bf16x8*)(bB + (wn * 64 + ni * 16 + cl) * 32 + p * 8);
#pragma unroll
    for (int mi = 0; mi < 4; mi++)
#pragma unroll
      for (int ni = 0; ni < 4; ni++)
        acc[mi][ni] = __builtin_amdgcn_mfma_f32_16x16x32_bf16(af[mi], bfr[ni], acc[mi][ni], 0, 0, 0);
  }

#pragma unroll
  for (int mi = 0; mi < 4; mi++)
#pragma unroll
    for (int ni = 0; ni < 4; ni++)
#pragma unroll
      for (int r2 = 0; r2 < 4; r2++) {
        int row = row0 + wm * 64 + mi * 16 + cq * 4 + r2;
        int col = col0 + wn * 64 + ni * 16 + cl;
        Cp[(size_t)sk * MM * NN + (size_t)row * NN + col] = __float2bfloat16(acc[mi][ni][r2]);
      }
}

// ---------------- GEMM C: 64x128 tile (conv3, mlp1), A dbuf + B chunk-dbuf, 4 blocks/CU --
template <int MODE, int TIN_, int TOUT_, int SS, int PP, int KK, int NN, int EPI, int SPLITK, int MM>
__global__ __launch_bounds__(256, 4) void k_gemmC(const __hip_bfloat16* __restrict__ A,
                                                  const __hip_bfloat16* __restrict__ Bt,
                                                  const float* __restrict__ bias,
                                                  __hip_bfloat16* __restrict__ Cout) {
  __shared__ __align__(16) __hip_bfloat16 sA[2][64 * 32];
  __shared__ __align__(16) __hip_bfloat16 sB[2][2][128 * 32];  // [chunk-buf][sub][...]
  const int tid = threadIdx.x;
  const int lane = tid & 63;
  const int wave = tid >> 6;
  const int wm = wave >> 1, wn = wave & 1;
  constexpr int nt = NN / 128;
  constexpr int PS = (MM / 512) * nt;
  constexpr int KBT = KK / 32;
  const int blk = blockIdx.x;
  const int xs = blk & 7, sl = blk >> 3;
  const int sk = sl / PS, rem = sl % PS;
  const int row0 = ((rem / nt) * 8 + xs) * 64;
  const int col0 = (rem % nt) * 128;
  const int kb0 = (sk * KBT) / SPLITK, kb1 = ((sk + 1) * KBT) / SPLITK;
  const int cq = lane >> 4, cl = lane & 15;

  const char* aP;
  const char* bP[2];

  auto stageA = [&](int kb, int buf) {
    bool recalc = (kb == kb0) || (MODE == 1 && (kb & 15) == 0);
    if (recalc) {
      int m = tid >> 2, kc = tid & 3;
      int kcs = kc ^ (m & 3);
      size_t ga;
      if (MODE == 0) {
        ga = (size_t)(row0 + m) * KK + kb * 32 + kcs * 8;
      } else {
        int r = row0 + m;
        int bb = r / TOUT_;
        int t = r - bb * TOUT_;
        int k = (kb * 32) >> 9;
        int ci = ((kb * 32) & 511) + kcs * 8;
        int gt = refl(t * SS - PP + k, TIN_);
        ga = (((size_t)(bb * TIN_ + gt)) << 9) + ci;
      }
      aP = (const char*)(A + ga);
    }
    gld16((char*)&sA[buf][0] + tid * 16, aP);
    aP += 64;
  };

  auto stageB = [&](int buf, bool doSub1) {
#pragma unroll
    for (int rr = 0; rr < 2; rr++) {
      gld16((char*)&sB[buf][0][0] + (rr * 256 + tid) * 16, bP[rr]);
      if (doSub1) gld16((char*)&sB[buf][1][0] + (rr * 256 + tid) * 16, bP[rr] + 64);
      bP[rr] += 128;
    }
  };

#pragma unroll
  for (int rr = 0; rr < 2; rr++) {
    int c = rr * 256 + tid;
    int n = c >> 2, kc = c & 3;
    int kcs = kc ^ (n & 3);
    bP[rr] = (const char*)(Bt + (size_t)(col0 + n) * KK + kb0 * 32 + kcs * 8);
  }

  f32x4 acc[2][4];
  const f32x4 zz = {0.f, 0.f, 0.f, 0.f};
#pragma unroll
  for (int mi = 0; mi < 2; mi++)
#pragma unroll
    for (int ni = 0; ni < 4; ni++) acc[mi][ni] = zz;

  stageA(kb0, 0);
  stageB(0, kb0 + 1 < kb1);

  const int p = cq ^ (cl & 3);
  for (int kb = kb0; kb < kb1; kb++) {
    const int jj = kb - kb0;
    __syncthreads();
    if (kb + 1 < kb1) stageA(kb + 1, (jj + 1) & 1);
    if (((jj & 1) == 0) && (kb + 2 < kb1)) stageB(((jj >> 1) + 1) & 1, kb + 3 < kb1);
    const short* bA = (const short*)&sA[jj & 1][0];
    const short* bB = (const short*)&sB[(jj >> 1) & 1][jj & 1][0];
    bf16x8 af[2], bfr[4];
#pragma unroll
    for (int mi = 0; mi < 2; mi++)
      af[mi] = *(const bf16x8*)(bA + (wm * 32 + mi * 16 + cl) * 32 + p * 8);
#pragma unroll
    for (int ni = 0; ni < 4; ni++)
      bfr[ni] = *(const bf16x8*)(bB + (wn * 64 + ni * 16 + cl) * 32 + p * 8);
#pragma unroll
    for (int mi = 0; mi < 2; mi++)
#pragma unroll
      for (int ni = 0; ni < 4; ni++)
        acc[mi][ni] = __builtin_amdgcn_mfma_f32_16x16x32_bf16(af[mi], bfr[ni], acc[mi][ni], 0, 0, 0);
  }

#pragma unroll
  for (int mi = 0; mi < 2; mi++)
#pragma unroll
    for (int ni = 0; ni < 4; ni++)
#pragma unroll
      for (int r2 = 0; r2 < 4; r2++) {
        int row = row0 + wm * 32 + mi * 16 + cq * 4 + r2;
        int col = col0 + wn * 64 + ni * 16 + cl;
        float v = acc[mi][ni][r2];
        if (EPI == 1) {
          v += bias[col];
          v = 0.5f * v * (1.f + erff(v * 0.70710678118654752f));
          Cout[(size_t)row * NN + col] = __float2bfloat16(v);
        } else {
          Cout[(size_t)sk * MM * NN + (size_t)row * NN + col] = __float2bfloat16(v);
        }
      }
}

// ---------------- ChannelNorm (+conv bias, sum NS bf16 split-K partials) + ReLU -> bf16
template <int NS>
__global__ __launch_bounds__(512) void k_cnorm(const __hip_bfloat16* __restrict__ g,
                                               const float* __restrict__ cb,
                                               const float* __restrict__ gw, const float* __restrict__ gb,
                                               __hip_bfloat16* __restrict__ out, size_t stride) {
  int wave = threadIdx.x >> 6, lane = threadIdx.x & 63;
  size_t row = (size_t)blockIdx.x * 8 + wave;
  float v[8];
  {
    float4 c0 = *(const float4*)(cb + lane * 8), c1 = *(const float4*)(cb + lane * 8 + 4);
    v[0] = c0.x; v[1] = c0.y; v[2] = c0.z; v[3] = c0.w;
    v[4] = c1.x; v[5] = c1.y; v[6] = c1.z; v[7] = c1.w;
  }
#pragma unroll
  for (int s = 0; s < NS; s++) add_bf8(g + s * stride + row * NC + lane * 8, v);
  float s = 0.f, q = 0.f;
#pragma unroll
  for (int j = 0; j < 8; j++) { s += v[j]; q += v[j] * v[j]; }
#pragma unroll
  for (int off = 32; off > 0; off >>= 1) {
    s += __shfl_xor(s, off, 64);
    q += __shfl_xor(q, off, 64);
  }
  float mean = s * (1.f / NC);
  float var = fmaxf((q - s * s * (1.f / NC)) * (1.f / (NC - 1)), 0.f);
  float rstd = rsqrtf(var + EPSF);
  float4 w0 = *(const float4*)(gw + lane * 8), w1 = *(const float4*)(gw + lane * 8 + 4);
  float4 b0 = *(const float4*)(gb + lane * 8), b1 = *(const float4*)(gb + lane * 8 + 4);
  float gwv[8] = {w0.x, w0.y, w0.z, w0.w, w1.x, w1.y, w1.z, w1.w};
  float gbv[8] = {b0.x, b0.y, b0.z, b0.w, b1.x, b1.y, b1.z, b1.w};
  union { __hip_bfloat16 h[8]; uint4 u; } pk;
#pragma unroll
  for (int j = 0; j < 8; j++)
    pk.h[j] = __float2bfloat16(fmaxf((v[j] - mean) * rstd * gwv[j] + gbv[j], 0.f));
  *(uint4*)(out + row * NC + lane * 8) = pk.u;
}

__device__ __forceinline__ float dfun(float cv, int n) {
  float d = fmaxf(cv - (float)n, 0.f);
  if (n < TN - 1) d = fminf(d, 1.f);
  return d;
}

// ---------------- cooperative tail: head (sum 3 partials + GELU dot w3 + sigmoid)
// then grid-sync, then cumsum+pool+final ChannelNorm. Fuses the last two launches
// into one (probe of the launch-overhead theory; 10 launches -> 9).
// Grid 256 x 512: head = 8 rows/block (4 elems/thread), pool = 4 (b,n) items/block.
__global__ __launch_bounds__(512) void k_tail(const __hip_bfloat16* __restrict__ g,
                                              const float* __restrict__ b2,
                                              const float* __restrict__ w3, const float* __restrict__ b3,
                                              float* __restrict__ imp,
                                              const __hip_bfloat16* __restrict__ f,
                                              const float* __restrict__ gw, const float* __restrict__ gb,
                                              float* __restrict__ out) {
  __shared__ float red[16];
  __shared__ float wt[T3];
  __shared__ float wsum[8];
  const int tid = threadIdx.x, lane = tid & 63, wid = tid >> 6;

  // ---- phase 1: importance head, rows blk*8 .. blk*8+7 ----
#pragma unroll 1
  for (int rr = 0; rr < 8; rr++) {
    int row = blockIdx.x * 8 + rr;
    int c = tid * 4;
    float v[4];
    {
      float4 x0 = *(const float4*)(b2 + c);
      v[0] = x0.x; v[1] = x0.y; v[2] = x0.z; v[3] = x0.w;
    }
#pragma unroll
    for (int s = 0; s < 3; s++) {
      union { uint2 u; __hip_bfloat16 h[4]; } pk;
      pk.u = *(const uint2*)(g + (size_t)s * (2048 * DM) + (size_t)row * DM + c);
#pragma unroll
      for (int j = 0; j < 4; j++) v[j] += __bfloat162float(pk.h[j]);
    }
    float4 w0 = *(const float4*)(w3 + c);
    float wv[4] = {w0.x, w0.y, w0.z, w0.w};
    float a = 0.f;
#pragma unroll
    for (int j = 0; j < 4; j++) {
      float z = 0.5f * v[j] * (1.f + erff(v[j] * 0.70710678118654752f));
      a += z * wv[j];
    }
#pragma unroll
    for (int off = 32; off > 0; off >>= 1) a += __shfl_down(a, off, 64);
    __syncthreads();  // protect red reuse across rr
    if (lane == 0) red[wid] = a;
    __syncthreads();
    if (tid == 0) {
      float s = b3[0];
#pragma unroll
      for (int i = 0; i < 8; i++) s += red[i];
      imp[row] = 1.f / (1.f + expf(-s)) + TEMPF;
    }
  }

  cooperative_groups::this_grid().sync();

  // ---- phase 2: pool + final ChannelNorm, items blk*4 .. blk*4+3 ----
#pragma unroll 1
  for (int q = 0; q < 4; q++) {
    __syncthreads();  // protect wt/wsum reuse across q
    int idx = blockIdx.x * 4 + q;
    int b = idx / TN, n = idx % TN;
    int wave = wid;
    float own = imp[b * T3 + tid];
    float s = own;
#pragma unroll
    for (int off = 1; off < 64; off <<= 1) {
      float t = __shfl_up(s, off, 64);
      if (lane >= off) s += t;
    }
    if (lane == 63) wsum[wave] = s;
    __syncthreads();
    float prefix = 0.f, total = 0.f;
#pragma unroll
    for (int w = 0; w < 8; w++) {
      float ws_ = wsum[w];
      total += ws_;
      if (w < wave) prefix += ws_;
    }
    float scale = (float)TN / total;
    float incl = (prefix + s) * scale;
    float excl = (prefix + s - own) * scale;
    wt[tid] = dfun(incl, n) - dfun(excl, n);
    __syncthreads();
    float acc = 0.f;
    for (int t = 0; t < T3; t++) {
      float w = wt[t];
      if (w != 0.f) acc += w * __bfloat162float(f[((size_t)b * T3 + t) * NC + tid]);
    }
    float sv = acc, qq = acc * acc;
    blk_sum2_512(sv, qq, red);
    float mean = sv * (1.f / NC);
    float var = fmaxf((qq - sv * sv * (1.f / NC)) * (1.f / (NC - 1)), 0.f);
    float y = (acc - mean) * rsqrtf(var + EPSF) * gw[tid] + gb[tid];
    out[((size_t)b * NC + tid) * TN + n] = fmaxf(y, 0.f);
  }
}

extern "C" void kernel_launch(void* const* d_in, const int* in_sizes, int n_in,
                              void* d_out, int out_size, void* d_ws, size_t ws_size,
                              hipStream_t stream) {
  const float* x   = (const float*)d_in[0];
  const float* c0w = (const float*)d_in[1];  const float* c0b = (const float*)d_in[2];
  const float* c1w = (const float*)d_in[3];  const float* c1b = (const float*)d_in[4];
  const float* c2w = (const float*)d_in[5];  const float* c2b = (const float*)d_in[6];
  const float* c3w = (const float*)d_in[7];  const float* c3b = (const float*)d_in[8];
  const float* mw1 = (const float*)d_in[9];  const float* mb1 = (const float*)d_in[10];
  const float* mw2 = (const float*)d_in[11]; const float* mb2 = (const float*)d_in[12];
  const float* mw3 = (const float*)d_in[13]; const float* mb3 = (const float*)d_in[14];
  const float* n0w = (const float*)d_in[15]; const float* n0b = (const float*)d_in[16];
  const float* n1w = (const float*)d_in[17]; const float* n1b = (const float*)d_in[18];
  const float* n2w = (const float*)d_in[19]; const float* n2b = (const float*)d_in[20];
  const float* n3w = (const float*)d_in[21]; const float* n3b = (const float*)d_in[22];
  const float* n4w = (const float*)d_in[23]; const float* n4b = (const float*)d_in[24];

  char* base = (char*)d_ws;
  // Workspace map (MiB). Peak 82 MiB (R8 layout).
  __hip_bfloat16* h0b  = (__hip_bfloat16*)(base);                     // [0,32): conv0 out; dead after conv1-gemm
  __hip_bfloat16* h1b  = (__hip_bfloat16*)(base);                     // reuse [0,8)
  __hip_bfloat16* h2b  = (__hip_bfloat16*)(base + (8u << 20));        // reuse [8,12)
  __hip_bfloat16* h3b  = (__hip_bfloat16*)(base + (12u << 20));       // reuse [12,14)
  __hip_bfloat16* z1b  = (__hip_bfloat16*)(base + (14u << 20));       // reuse [14,22)
  float*          imp  = (float*)(base + (22u << 20));                // reuse [22,+8K)
  __hip_bfloat16* g    = (__hip_bfloat16*)(base + (32u << 20));       // [32,64): bf16 split-K partials
  __hip_bfloat16* wm1t = (__hip_bfloat16*)(base + (64u << 20));       // [64,66)
  __hip_bfloat16* wt2  = (__hip_bfloat16*)(base + (66u << 20));       // [66,68)
  __hip_bfloat16* wt3  = (__hip_bfloat16*)(base + (68u << 20));       // [68,70)
  __hip_bfloat16* wt1  = (__hip_bfloat16*)(base + (70u << 20));       // [70,74)
  __hip_bfloat16* wm2t = (__hip_bfloat16*)(base + (74u << 20));       // [74,82)
  float* outp = (float*)d_out;

  k_init<<<4096 + 6656, 512, 0, stream>>>(x, c0w, c0b, n0w, n0b, h0b,
                                          c1w, c2w, c3w, mw1, mw2, wt1, wt2, wt3, wm1t, wm2t);

  // conv1: 128x128 tile, SK3 -> 768 blocks (3/CU), B chunk-staged — the 315.1us config.
  k_gemmB<1, 8192, 2048, 4, 2, 4096, 512, 3, 8192><<<768, 256, 0, stream>>>(h0b, wt1, g);
  k_cnorm<3><<<8192 / 8, 512, 0, stream>>>(g, c1b, n1w, n1b, h1b, (size_t)8192 * 512);
  // conv2: 128x128, SK6 -> 768 blocks (3/CU)
  k_gemmB<1, 2048, 1024, 2, 1, 2048, 512, 6, 4096><<<768, 256, 0, stream>>>(h1b, wt2, g);
  k_cnorm<6><<<4096 / 8, 512, 0, stream>>>(g, c2b, n2w, n2b, h2b, (size_t)4096 * 512);
  // conv3: 64x128, SK6 -> 768 blocks
  k_gemmC<1, 1024, 512, 2, 1, 2048, 512, 0, 6, 2048><<<768, 256, 0, stream>>>(h2b, wt3, c3b, g);
  k_cnorm<6><<<2048 / 8, 512, 0, stream>>>(g, c3b, n3w, n3b, h3b, (size_t)2048 * 512);
  // mlp1: 64x128, EPI=GELU -> 512 blocks
  k_gemmC<0, 0, 1, 0, 0, 512, 2048, 1, 1, 2048><<<512, 256, 0, stream>>>(h3b, wm1t, mb1, z1b);
  // mlp2: 128x128, SK3 -> 768 blocks
  k_gemmB<0, 0, 1, 0, 0, 2048, 2048, 3, 2048><<<768, 256, 0, stream>>>(z1b, wm2t, g);

  // fused head + pool (cooperative, 1 grid-sync). 256 blocks x 512 thr = 1 block/CU.
  {
    const __hip_bfloat16* g_c = g;
    const float* b2_c = mb2;
    const float* w3_c = mw3;
    const float* b3_c = mb3;
    float* imp_c = imp;
    const __hip_bfloat16* f_c = h3b;
    const float* gw_c = n4w;
    const float* gb_c = n4b;
    float* out_c = outp;
    void* args[9] = {&g_c, &b2_c, &w3_c, &b3_c, &imp_c, &f_c, &gw_c, &gb_c, &out_c};
    hipLaunchCooperativeKernel((const void*)k_tail, dim3(256), dim3(512), args, 0, stream);
  }
}

// Round 12
// 292.812 us; speedup vs baseline: 1.5699x; 1.5699x over previous
//
#include <hip/hip_runtime.h>
#include <hip/hip_bf16.h>
#include <math.h>

#define NB 4
#define LIN 40960
#define NC 512
#define T0 8192
#define T1 2048
#define T2 1024
#define T3 512
#define TN 256
#define DM 2048
#define EPSF 1e-5f
#define TEMPF 1e-5f

typedef __attribute__((ext_vector_type(8))) short bf16x8;
typedef __attribute__((ext_vector_type(4))) float f32x4;

__device__ __forceinline__ int refl(int t, int T) {
  if (t < 0) t = -t;
  if (t >= T) t = 2 * T - 2 - t;
  return t;
}

__device__ __forceinline__ void gld16(void* lds, const void* g) {
  __builtin_amdgcn_global_load_lds((const __attribute__((address_space(1))) unsigned int*)g,
                                   (__attribute__((address_space(3))) unsigned int*)lds, 16, 0, 0);
}

__device__ __forceinline__ void blk_sum2_512(float& a, float& b, float* scratch) {
#pragma unroll
  for (int off = 32; off > 0; off >>= 1) {
    a += __shfl_down(a, off, 64);
    b += __shfl_down(b, off, 64);
  }
  int lane = threadIdx.x & 63, wid = threadIdx.x >> 6;
  __syncthreads();
  if (lane == 0) { scratch[wid] = a; scratch[8 + wid] = b; }
  __syncthreads();
  float sa = 0.f, sb = 0.f;
#pragma unroll
  for (int i = 0; i < 8; i++) { sa += scratch[i]; sb += scratch[8 + i]; }
  a = sa; b = sb;
}

__device__ __forceinline__ void add_bf8(const __hip_bfloat16* p, float* v) {
  union { uint4 u; __hip_bfloat16 h[8]; } pk;
  pk.u = *(const uint4*)p;
#pragma unroll
  for (int j = 0; j < 8; j++) v[j] += __bfloat162float(pk.h[j]);
}

// ---------------- merged init: conv0 (blocks 0..4095) + weight prep ----------------
template <int KT>
__device__ __forceinline__ void prep_conv_body(const float* __restrict__ w, __hip_bfloat16* __restrict__ wt,
                                               int co, float* l) {
  const float* wb = w + (size_t)co * 512 * KT;
  for (int i = threadIdx.x; i < 512 * KT; i += 512) l[i] = wb[i];
  __syncthreads();
  __hip_bfloat16* wo = wt + (size_t)co * 512 * KT;
  for (int i = threadIdx.x; i < 512 * KT; i += 512) {
    int kk = i >> 9, ci = i & 511;
    wo[i] = __float2bfloat16(l[ci * KT + kk]);
  }
}

template <int KD, int ND>
__device__ __forceinline__ void prep_mlp_body(const float* __restrict__ w, __hip_bfloat16* __restrict__ wt,
                                              int bidx, float* sbuf) {
  float(*tile)[33] = (float(*)[33])sbuf;
  int bx = bidx % (ND / 32);
  int by = bidx / (ND / 32);
  int tx = threadIdx.x & 31, ty = threadIdx.x >> 5;  // ty 0..15
#pragma unroll
  for (int i = 0; i < 32; i += 16)
    tile[ty + i][tx] = w[(size_t)(by * 32 + ty + i) * ND + bx * 32 + tx];
  __syncthreads();
#pragma unroll
  for (int i = 0; i < 32; i += 16)
    wt[(size_t)(bx * 32 + ty + i) * KD + by * 32 + tx] = __float2bfloat16(tile[tx][ty + i]);
}

__device__ __forceinline__ void conv0_body(const float* __restrict__ x, const float* __restrict__ w,
                                           const float* __restrict__ bias, const float* __restrict__ gw,
                                           const float* __restrict__ gb, __hip_bfloat16* __restrict__ out,
                                           int blk, float* smem) {
  float* xv = smem;
  float* tb = smem + 64;
  float* stats = smem + 4672;
  int b = blk / (T0 / 8);
  int t0 = (blk % (T0 / 8)) * 8;
  int tid = threadIdx.x;
  if (tid < 45) xv[tid] = x[(size_t)b * LIN + refl(t0 * 5 - 3 + tid, LIN)];
  __syncthreads();
  float wk[10];
#pragma unroll
  for (int k = 0; k < 10; k++) wk[k] = w[tid * 10 + k];
  float bs = bias[tid];
  float acc[8];
#pragma unroll
  for (int tt = 0; tt < 8; tt++) {
    float a = bs;
#pragma unroll
    for (int k = 0; k < 10; k++) a += xv[tt * 5 + k] * wk[k];
    acc[tt] = a;
    tb[tid * 9 + tt] = a;
  }
  __syncthreads();
  int wave = tid >> 6, lane = tid & 63;
  float s = 0.f, q = 0.f;
#pragma unroll
  for (int j = 0; j < 8; j++) {
    float v = tb[(lane * 8 + j) * 9 + wave];
    s += v; q += v * v;
  }
#pragma unroll
  for (int off = 32; off > 0; off >>= 1) {
    s += __shfl_xor(s, off, 64);
    q += __shfl_xor(q, off, 64);
  }
  if (lane == 0) {
    float mean = s * (1.f / NC);
    float var = fmaxf((q - s * s * (1.f / NC)) * (1.f / (NC - 1)), 0.f);
    stats[wave] = mean;
    stats[8 + wave] = rsqrtf(var + EPSF);
  }
  __syncthreads();
  float gwv = gw[tid], gbv = gb[tid];
#pragma unroll
  for (int tt = 0; tt < 8; tt++) {
    float y = (acc[tt] - stats[tt]) * stats[8 + tt] * gwv + gbv;
    out[((size_t)(b * T0 + t0 + tt)) * NC + tid] = __float2bfloat16(fmaxf(y, 0.f));
  }
}

__global__ __launch_bounds__(512) void k_init(const float* x, const float* c0w, const float* c0b,
                                              const float* n0w, const float* n0b, __hip_bfloat16* h0b,
                                              const float* c1w, const float* c2w, const float* c3w,
                                              const float* mw1, const float* mw2,
                                              __hip_bfloat16* wt1, __hip_bfloat16* wt2,
                                              __hip_bfloat16* wt3, __hip_bfloat16* wm1t,
                                              __hip_bfloat16* wm2t) {
  __shared__ float smem[4688];
  int b = blockIdx.x;
  if (b < 4096) conv0_body(x, c0w, c0b, n0w, n0b, h0b, b, smem);
  else if (b < 4608) prep_conv_body<8>(c1w, wt1, b - 4096, smem);
  else if (b < 5120) prep_conv_body<4>(c2w, wt2, b - 4608, smem);
  else if (b < 5632) prep_conv_body<4>(c3w, wt3, b - 5120, smem);
  else if (b < 6656) prep_mlp_body<512, 2048>(mw1, wm1t, b - 5632, smem);
  else prep_mlp_body<2048, 2048>(mw2, wm2t, b - 6656, smem);
}

// ---------------- GEMM B: 128x128 tile (wave=64x64), BK=32, A dbuf + B chunk-dbuf (64K),
// SK, strength-reduced. 3 blocks/CU (LDS 48KB). The measured-best-total config (315.1us).
template <int MODE, int TIN_, int TOUT_, int SS, int PP, int KK, int NN, int SPLITK, int MM>
__global__ __launch_bounds__(256) void k_gemmB(const __hip_bfloat16* __restrict__ A,
                                               const __hip_bfloat16* __restrict__ Bt,
                                               __hip_bfloat16* __restrict__ Cp) {
  __shared__ __align__(16) __hip_bfloat16 sA[2][128 * 32];
  __shared__ __align__(16) __hip_bfloat16 sB[2][2][128 * 32];  // [chunk-buf][sub][...]
  const int tid = threadIdx.x;
  const int lane = tid & 63;
  const int wave = tid >> 6;
  const int wm = wave >> 1, wn = wave & 1;
  constexpr int nt = NN / 128;
  constexpr int PS = (MM / 1024) * nt;
  constexpr int KBT = KK / 32;
  const int blk = blockIdx.x;
  const int xs = blk & 7, sl = blk >> 3;
  const int sk = sl / PS, rem = sl % PS;
  const int row0 = ((rem / nt) * 8 + xs) * 128;
  const int col0 = (rem % nt) * 128;
  const int kb0 = (sk * KBT) / SPLITK, kb1 = ((sk + 1) * KBT) / SPLITK;
  const int cq = lane >> 4, cl = lane & 15;

  const char* aP[2];
  const char* bP[2];

  auto stageA = [&](int kb, int buf) {
    bool recalc = (kb == kb0) || (MODE == 1 && (kb & 15) == 0);
    if (recalc) {
#pragma unroll
      for (int rr = 0; rr < 2; rr++) {
        int c = rr * 256 + tid;
        int m = c >> 2, kc = c & 3;
        int kcs = kc ^ (m & 3);
        size_t ga;
        if (MODE == 0) {
          ga = (size_t)(row0 + m) * KK + kb * 32 + kcs * 8;
        } else {
          int r = row0 + m;
          int bb = r / TOUT_;
          int t = r - bb * TOUT_;
          int k = (kb * 32) >> 9;
          int ci = ((kb * 32) & 511) + kcs * 8;
          int gt = refl(t * SS - PP + k, TIN_);
          ga = (((size_t)(bb * TIN_ + gt)) << 9) + ci;
        }
        aP[rr] = (const char*)(A + ga);
      }
    }
#pragma unroll
    for (int rr = 0; rr < 2; rr++) {
      gld16((char*)&sA[buf][0] + (rr * 256 + tid) * 16, aP[rr]);
      aP[rr] += 64;
    }
  };

  // Stages a full 64-K chunk (2 sub-tiles) into chunk-buf `buf`; advances bP by 128B.
  auto stageB = [&](int buf, bool doSub1) {
#pragma unroll
    for (int rr = 0; rr < 2; rr++) {
      gld16((char*)&sB[buf][0][0] + (rr * 256 + tid) * 16, bP[rr]);
      if (doSub1) gld16((char*)&sB[buf][1][0] + (rr * 256 + tid) * 16, bP[rr] + 64);
      bP[rr] += 128;
    }
  };

#pragma unroll
  for (int rr = 0; rr < 2; rr++) {
    int c = rr * 256 + tid;
    int n = c >> 2, kc = c & 3;
    int kcs = kc ^ (n & 3);
    bP[rr] = (const char*)(Bt + (size_t)(col0 + n) * KK + kb0 * 32 + kcs * 8);
  }

  f32x4 acc[4][4];
  const f32x4 zz = {0.f, 0.f, 0.f, 0.f};
#pragma unroll
  for (int mi = 0; mi < 4; mi++)
#pragma unroll
    for (int ni = 0; ni < 4; ni++) acc[mi][ni] = zz;

  stageA(kb0, 0);
  stageB(0, kb0 + 1 < kb1);

  const int p = cq ^ (cl & 3);
  for (int kb = kb0; kb < kb1; kb++) {
    const int jj = kb - kb0;
    __syncthreads();
    if (kb + 1 < kb1) stageA(kb + 1, (jj + 1) & 1);
    if (((jj & 1) == 0) && (kb + 2 < kb1)) stageB(((jj >> 1) + 1) & 1, kb + 3 < kb1);
    const short* bA = (const short*)&sA[jj & 1][0];
    const short* bB = (const short*)&sB[(jj >> 1) & 1][jj & 1][0];
    bf16x8 af[4], bfr[4];
#pragma unroll
    for (int mi = 0; mi < 4; mi++)
      af[mi] = *(const bf16x8*)(bA + (wm * 64 + mi * 16 + cl) * 32 + p * 8);
#pragma unroll
    for (int ni = 0; ni < 4; ni++)
      bfr[ni] = *(const bf16x8*)(bB + (wn * 64 + ni * 16 + cl) * 32 + p * 8);
#pragma unroll
    for (int mi = 0; mi < 4; mi++)
#pragma unroll
      for (int ni = 0; ni < 4; ni++)
        acc[mi][ni] = __builtin_amdgcn_mfma_f32_16x16x32_bf16(af[mi], bfr[ni], acc[mi][ni], 0, 0, 0);
  }

#pragma unroll
  for (int mi = 0; mi < 4; mi++)
#pragma unroll
    for (int ni = 0; ni < 4; ni++)
#pragma unroll
      for (int r2 = 0; r2 < 4; r2++) {
        int row = row0 + wm * 64 + mi * 16 + cq * 4 + r2;
        int col = col0 + wn * 64 + ni * 16 + cl;
        Cp[(size_t)sk * MM * NN + (size_t)row * NN + col] = __float2bfloat16(acc[mi][ni][r2]);
      }
}

// ---------------- GEMM C: 64x128 tile (conv3, mlp1), A dbuf + B chunk-dbuf, 4 blocks/CU --
template <int MODE, int TIN_, int TOUT_, int SS, int PP, int KK, int NN, int EPI, int SPLITK, int MM>
__global__ __launch_bounds__(256, 4) void k_gemmC(const __hip_bfloat16* __restrict__ A,
                                                  const __hip_bfloat16* __restrict__ Bt,
                                                  const float* __restrict__ bias,
                                                  __hip_bfloat16* __restrict__ Cout) {
  __shared__ __align__(16) __hip_bfloat16 sA[2][64 * 32];
  __shared__ __align__(16) __hip_bfloat16 sB[2][2][128 * 32];  // [chunk-buf][sub][...]
  const int tid = threadIdx.x;
  const int lane = tid & 63;
  const int wave = tid >> 6;
  const int wm = wave >> 1, wn = wave & 1;
  constexpr int nt = NN / 128;
  constexpr int PS = (MM / 512) * nt;
  constexpr int KBT = KK / 32;
  const int blk = blockIdx.x;
  const int xs = blk & 7, sl = blk >> 3;
  const int sk = sl / PS, rem = sl % PS;
  const int row0 = ((rem / nt) * 8 + xs) * 64;
  const int col0 = (rem % nt) * 128;
  const int kb0 = (sk * KBT) / SPLITK, kb1 = ((sk + 1) * KBT) / SPLITK;
  const int cq = lane >> 4, cl = lane & 15;

  const char* aP;
  const char* bP[2];

  auto stageA = [&](int kb, int buf) {
    bool recalc = (kb == kb0) || (MODE == 1 && (kb & 15) == 0);
    if (recalc) {
      int m = tid >> 2, kc = tid & 3;
      int kcs = kc ^ (m & 3);
      size_t ga;
      if (MODE == 0) {
        ga = (size_t)(row0 + m) * KK + kb * 32 + kcs * 8;
      } else {
        int r = row0 + m;
        int bb = r / TOUT_;
        int t = r - bb * TOUT_;
        int k = (kb * 32) >> 9;
        int ci = ((kb * 32) & 511) + kcs * 8;
        int gt = refl(t * SS - PP + k, TIN_);
        ga = (((size_t)(bb * TIN_ + gt)) << 9) + ci;
      }
      aP = (const char*)(A + ga);
    }
    gld16((char*)&sA[buf][0] + tid * 16, aP);
    aP += 64;
  };

  auto stageB = [&](int buf, bool doSub1) {
#pragma unroll
    for (int rr = 0; rr < 2; rr++) {
      gld16((char*)&sB[buf][0][0] + (rr * 256 + tid) * 16, bP[rr]);
      if (doSub1) gld16((char*)&sB[buf][1][0] + (rr * 256 + tid) * 16, bP[rr] + 64);
      bP[rr] += 128;
    }
  };

#pragma unroll
  for (int rr = 0; rr < 2; rr++) {
    int c = rr * 256 + tid;
    int n = c >> 2, kc = c & 3;
    int kcs = kc ^ (n & 3);
    bP[rr] = (const char*)(Bt + (size_t)(col0 + n) * KK + kb0 * 32 + kcs * 8);
  }

  f32x4 acc[2][4];
  const f32x4 zz = {0.f, 0.f, 0.f, 0.f};
#pragma unroll
  for (int mi = 0; mi < 2; mi++)
#pragma unroll
    for (int ni = 0; ni < 4; ni++) acc[mi][ni] = zz;

  stageA(kb0, 0);
  stageB(0, kb0 + 1 < kb1);

  const int p = cq ^ (cl & 3);
  for (int kb = kb0; kb < kb1; kb++) {
    const int jj = kb - kb0;
    __syncthreads();
    if (kb + 1 < kb1) stageA(kb + 1, (jj + 1) & 1);
    if (((jj & 1) == 0) && (kb + 2 < kb1)) stageB(((jj >> 1) + 1) & 1, kb + 3 < kb1);
    const short* bA = (const short*)&sA[jj & 1][0];
    const short* bB = (const short*)&sB[(jj >> 1) & 1][jj & 1][0];
    bf16x8 af[2], bfr[4];
#pragma unroll
    for (int mi = 0; mi < 2; mi++)
      af[mi] = *(const bf16x8*)(bA + (wm * 32 + mi * 16 + cl) * 32 + p * 8);
#pragma unroll
    for (int ni = 0; ni < 4; ni++)
      bfr[ni] = *(const bf16x8*)(bB + (wn * 64 + ni * 16 + cl) * 32 + p * 8);
#pragma unroll
    for (int mi = 0; mi < 2; mi++)
#pragma unroll
      for (int ni = 0; ni < 4; ni++)
        acc[mi][ni] = __builtin_amdgcn_mfma_f32_16x16x32_bf16(af[mi], bfr[ni], acc[mi][ni], 0, 0, 0);
  }

#pragma unroll
  for (int mi = 0; mi < 2; mi++)
#pragma unroll
    for (int ni = 0; ni < 4; ni++)
#pragma unroll
      for (int r2 = 0; r2 < 4; r2++) {
        int row = row0 + wm * 32 + mi * 16 + cq * 4 + r2;
        int col = col0 + wn * 64 + ni * 16 + cl;
        float v = acc[mi][ni][r2];
        if (EPI == 1) {
          v += bias[col];
          v = 0.5f * v * (1.f + erff(v * 0.70710678118654752f));
          Cout[(size_t)row * NN + col] = __float2bfloat16(v);
        } else {
          Cout[(size_t)sk * MM * NN + (size_t)row * NN + col] = __float2bfloat16(v);
        }
      }
}

// ---------------- ChannelNorm (+conv bias, sum NS bf16 split-K partials) + ReLU -> bf16
template <int NS>
__global__ __launch_bounds__(512) void k_cnorm(const __hip_bfloat16* __restrict__ g,
                                               const float* __restrict__ cb,
                                               const float* __restrict__ gw, const float* __restrict__ gb,
                                               __hip_bfloat16* __restrict__ out, size_t stride) {
  int wave = threadIdx.x >> 6, lane = threadIdx.x & 63;
  size_t row = (size_t)blockIdx.x * 8 + wave;
  float v[8];
  {
    float4 c0 = *(const float4*)(cb + lane * 8), c1 = *(const float4*)(cb + lane * 8 + 4);
    v[0] = c0.x; v[1] = c0.y; v[2] = c0.z; v[3] = c0.w;
    v[4] = c1.x; v[5] = c1.y; v[6] = c1.z; v[7] = c1.w;
  }
#pragma unroll
  for (int s = 0; s < NS; s++) add_bf8(g + s * stride + row * NC + lane * 8, v);
  float s = 0.f, q = 0.f;
#pragma unroll
  for (int j = 0; j < 8; j++) { s += v[j]; q += v[j] * v[j]; }
#pragma unroll
  for (int off = 32; off > 0; off >>= 1) {
    s += __shfl_xor(s, off, 64);
    q += __shfl_xor(q, off, 64);
  }
  float mean = s * (1.f / NC);
  float var = fmaxf((q - s * s * (1.f / NC)) * (1.f / (NC - 1)), 0.f);
  float rstd = rsqrtf(var + EPSF);
  float4 w0 = *(const float4*)(gw + lane * 8), w1 = *(const float4*)(gw + lane * 8 + 4);
  float4 b0 = *(const float4*)(gb + lane * 8), b1 = *(const float4*)(gb + lane * 8 + 4);
  float gwv[8] = {w0.x, w0.y, w0.z, w0.w, w1.x, w1.y, w1.z, w1.w};
  float gbv[8] = {b0.x, b0.y, b0.z, b0.w, b1.x, b1.y, b1.z, b1.w};
  union { __hip_bfloat16 h[8]; uint4 u; } pk;
#pragma unroll
  for (int j = 0; j < 8; j++)
    pk.h[j] = __float2bfloat16(fmaxf((v[j] - mean) * rstd * gwv[j] + gbv[j], 0.f));
  *(uint4*)(out + row * NC + lane * 8) = pk.u;
}

// ---------------- fused head: sum NS bf16 partials + bias + GELU, dot w3, sigmoid ----
template <int NS>
__global__ __launch_bounds__(256) void k_head(const __hip_bfloat16* __restrict__ g,
                                              const float* __restrict__ b2,
                                              const float* __restrict__ w3, const float* __restrict__ b3,
                                              float* __restrict__ imp) {
  __shared__ float red[4];
  int row = blockIdx.x, tid = threadIdx.x;
  int c = tid * 8;
  float v[8];
  {
    float4 x0 = *(const float4*)(b2 + c), x1 = *(const float4*)(b2 + c + 4);
    v[0] = x0.x; v[1] = x0.y; v[2] = x0.z; v[3] = x0.w;
    v[4] = x1.x; v[5] = x1.y; v[6] = x1.z; v[7] = x1.w;
  }
#pragma unroll
  for (int s = 0; s < NS; s++) add_bf8(g + (size_t)s * (2048 * DM) + (size_t)row * DM + c, v);
  float a = 0.f;
  float4 w0 = *(const float4*)(w3 + c), w1 = *(const float4*)(w3 + c + 4);
  float wv[8] = {w0.x, w0.y, w0.z, w0.w, w1.x, w1.y, w1.z, w1.w};
#pragma unroll
  for (int j = 0; j < 8; j++) {
    float z = 0.5f * v[j] * (1.f + erff(v[j] * 0.70710678118654752f));
    a += z * wv[j];
  }
#pragma unroll
  for (int off = 32; off > 0; off >>= 1) a += __shfl_down(a, off, 64);
  int lane = tid & 63, wid = tid >> 6;
  if (lane == 0) red[wid] = a;
  __syncthreads();
  if (tid == 0) {
    float s = red[0] + red[1] + red[2] + red[3] + b3[0];
    imp[row] = 1.f / (1.f + expf(-s)) + TEMPF;
  }
}

__device__ __forceinline__ float dfun(float cv, int n) {
  float d = fmaxf(cv - (float)n, 0.f);
  if (n < TN - 1) d = fminf(d, 1.f);
  return d;
}

// ---------------- fused cumsum + pool + final ChannelNorm + ReLU, write [B][C][TN] ----
// R11 discovery: the old t-loop was 512 serial single-outstanding LDS broadcasts
// (~120cy each, m117) ~= 29us/item — poolfinal was a hidden ~30us wall-time chunk.
// The nonzero support of wt for output n is a CONTIGUOUS t-range (cumsum monotone),
// typically 2-4 wide: find it with per-wave ballot + 8-entry min/max, loop only that.
// The if(w!=0) guard is kept, so the FP sum over nonzero terms is unchanged.
__global__ __launch_bounds__(512) void k_poolfinal(const __hip_bfloat16* __restrict__ f,
                                                   const float* __restrict__ imp,
                                                   const float* __restrict__ gw, const float* __restrict__ gb,
                                                   float* __restrict__ out) {
  __shared__ float wt[T3];
  __shared__ float wsum[8];
  __shared__ float red[16];
  __shared__ int rmin[8], rmax[8];
  int b = blockIdx.x / TN, n = blockIdx.x % TN;
  int tid = threadIdx.x, wave = tid >> 6, lane = tid & 63;
  float own = imp[b * T3 + tid];
  float s = own;
#pragma unroll
  for (int off = 1; off < 64; off <<= 1) {
    float t = __shfl_up(s, off, 64);
    if (lane >= off) s += t;
  }
  if (lane == 63) wsum[wave] = s;
  __syncthreads();
  float prefix = 0.f, total = 0.f;
#pragma unroll
  for (int w = 0; w < 8; w++) {
    float ws_ = wsum[w];
    total += ws_;
    if (w < wave) prefix += ws_;
  }
  float scale = (float)TN / total;
  float incl = (prefix + s) * scale;
  float excl = (prefix + s - own) * scale;
  float myw = dfun(incl, n) - dfun(excl, n);
  wt[tid] = myw;
  // locate the contiguous nonzero t-range
  unsigned long long m = __ballot(myw != 0.f);
  if (lane == 0) {
    rmin[wave] = m ? (wave * 64 + __ffsll(m) - 1) : T3;
    rmax[wave] = m ? (wave * 64 + 63 - __clzll(m)) : -1;
  }
  __syncthreads();
  int tmin = T3, tmax = -1;
#pragma unroll
  for (int w = 0; w < 8; w++) {
    tmin = min(tmin, rmin[w]);
    tmax = max(tmax, rmax[w]);
  }
  float acc = 0.f;
  for (int t = tmin; t <= tmax; t++) {
    float w = wt[t];
    if (w != 0.f) acc += w * __bfloat162float(f[((size_t)b * T3 + t) * NC + tid]);
  }
  float sv = acc, q = acc * acc;
  blk_sum2_512(sv, q, red);
  float mean = sv * (1.f / NC);
  float var = fmaxf((q - sv * sv * (1.f / NC)) * (1.f / (NC - 1)), 0.f);
  float y = (acc - mean) * rsqrtf(var + EPSF) * gw[tid] + gb[tid];
  out[((size_t)b * NC + tid) * TN + n] = fmaxf(y, 0.f);
}

extern "C" void kernel_launch(void* const* d_in, const int* in_sizes, int n_in,
                              void* d_out, int out_size, void* d_ws, size_t ws_size,
                              hipStream_t stream) {
  const float* x   = (const float*)d_in[0];
  const float* c0w = (const float*)d_in[1];  const float* c0b = (const float*)d_in[2];
  const float* c1w = (const float*)d_in[3];  const float* c1b = (const float*)d_in[4];
  const float* c2w = (const float*)d_in[5];  const float* c2b = (const float*)d_in[6];
  const float* c3w = (const float*)d_in[7];  const float* c3b = (const float*)d_in[8];
  const float* mw1 = (const float*)d_in[9];  const float* mb1 = (const float*)d_in[10];
  const float* mw2 = (const float*)d_in[11]; const float* mb2 = (const float*)d_in[12];
  const float* mw3 = (const float*)d_in[13]; const float* mb3 = (const float*)d_in[14];
  const float* n0w = (const float*)d_in[15]; const float* n0b = (const float*)d_in[16];
  const float* n1w = (const float*)d_in[17]; const float* n1b = (const float*)d_in[18];
  const float* n2w = (const float*)d_in[19]; const float* n2b = (const float*)d_in[20];
  const float* n3w = (const float*)d_in[21]; const float* n3b = (const float*)d_in[22];
  const float* n4w = (const float*)d_in[23]; const float* n4b = (const float*)d_in[24];

  char* base = (char*)d_ws;
  // Workspace map (MiB). Peak 82 MiB (R8 layout).
  __hip_bfloat16* h0b  = (__hip_bfloat16*)(base);                     // [0,32): conv0 out; dead after conv1-gemm
  __hip_bfloat16* h1b  = (__hip_bfloat16*)(base);                     // reuse [0,8)
  __hip_bfloat16* h2b  = (__hip_bfloat16*)(base + (8u << 20));        // reuse [8,12)
  __hip_bfloat16* h3b  = (__hip_bfloat16*)(base + (12u << 20));       // reuse [12,14)
  __hip_bfloat16* z1b  = (__hip_bfloat16*)(base + (14u << 20));       // reuse [14,22)
  float*          imp  = (float*)(base + (22u << 20));                // reuse [22,+8K)
  __hip_bfloat16* g    = (__hip_bfloat16*)(base + (32u << 20));       // [32,64): bf16 split-K partials
  __hip_bfloat16* wm1t = (__hip_bfloat16*)(base + (64u << 20));       // [64,66)
  __hip_bfloat16* wt2  = (__hip_bfloat16*)(base + (66u << 20));       // [66,68)
  __hip_bfloat16* wt3  = (__hip_bfloat16*)(base + (68u << 20));       // [68,70)
  __hip_bfloat16* wt1  = (__hip_bfloat16*)(base + (70u << 20));       // [70,74)
  __hip_bfloat16* wm2t = (__hip_bfloat16*)(base + (74u << 20));       // [74,82)
  float* outp = (float*)d_out;

  k_init<<<4096 + 6656, 512, 0, stream>>>(x, c0w, c0b, n0w, n0b, h0b,
                                          c1w, c2w, c3w, mw1, mw2, wt1, wt2, wt3, wm1t, wm2t);

  // conv1: 128x128 tile, SK3 -> 768 blocks (3/CU), B chunk-staged — the 315.1us config.
  k_gemmB<1, 8192, 2048, 4, 2, 4096, 512, 3, 8192><<<768, 256, 0, stream>>>(h0b, wt1, g);
  k_cnorm<3><<<8192 / 8, 512, 0, stream>>>(g, c1b, n1w, n1b, h1b, (size_t)8192 * 512);
  // conv2: 128x128, SK6 -> 768 blocks (3/CU)
  k_gemmB<1, 2048, 1024, 2, 1, 2048, 512, 6, 4096><<<768, 256, 0, stream>>>(h1b, wt2, g);
  k_cnorm<6><<<4096 / 8, 512, 0, stream>>>(g, c2b, n2w, n2b, h2b, (size_t)4096 * 512);
  // conv3: 64x128, SK6 -> 768 blocks
  k_gemmC<1, 1024, 512, 2, 1, 2048, 512, 0, 6, 2048><<<768, 256, 0, stream>>>(h2b, wt3, c3b, g);
  k_cnorm<6><<<2048 / 8, 512, 0, stream>>>(g, c3b, n3w, n3b, h3b, (size_t)2048 * 512);
  // mlp1: 64x128, EPI=GELU -> 512 blocks
  k_gemmC<0, 0, 1, 0, 0, 512, 2048, 1, 1, 2048><<<512, 256, 0, stream>>>(h3b, wm1t, mb1, z1b);
  // mlp2: 128x128, SK3 -> 768 blocks
  k_gemmB<0, 0, 1, 0, 0, 2048, 2048, 3, 2048><<<768, 256, 0, stream>>>(z1b, wm2t, g);

  k_head<3><<<NB * T3, 256, 0, stream>>>(g, mb2, mw3, mb3, imp);
  k_poolfinal<<<NB * TN, 512, 0, stream>>>(h3b, imp, n4w, n4b, outp);
}

// Round 14
// 292.031 us; speedup vs baseline: 1.5741x; 1.0027x over previous
//
#include <hip/hip_runtime.h>
#include <hip/hip_bf16.h>
#include <math.h>

#define NB 4
#define LIN 40960
#define NC 512
#define T0 8192
#define T1 2048
#define T2 1024
#define T3 512
#define TN 256
#define DM 2048
#define EPSF 1e-5f
#define TEMPF 1e-5f

typedef __attribute__((ext_vector_type(8))) short bf16x8;
typedef __attribute__((ext_vector_type(4))) float f32x4;

__device__ __forceinline__ int refl(int t, int T) {
  if (t < 0) t = -t;
  if (t >= T) t = 2 * T - 2 - t;
  return t;
}

__device__ __forceinline__ void gld16(void* lds, const void* g) {
  __builtin_amdgcn_global_load_lds((const __attribute__((address_space(1))) unsigned int*)g,
                                   (__attribute__((address_space(3))) unsigned int*)lds, 16, 0, 0);
}

__device__ __forceinline__ void blk_sum2_512(float& a, float& b, float* scratch) {
#pragma unroll
  for (int off = 32; off > 0; off >>= 1) {
    a += __shfl_down(a, off, 64);
    b += __shfl_down(b, off, 64);
  }
  int lane = threadIdx.x & 63, wid = threadIdx.x >> 6;
  __syncthreads();
  if (lane == 0) { scratch[wid] = a; scratch[8 + wid] = b; }
  __syncthreads();
  float sa = 0.f, sb = 0.f;
#pragma unroll
  for (int i = 0; i < 8; i++) { sa += scratch[i]; sb += scratch[8 + i]; }
  a = sa; b = sb;
}

__device__ __forceinline__ void add_bf8(const __hip_bfloat16* p, float* v) {
  union { uint4 u; __hip_bfloat16 h[8]; } pk;
  pk.u = *(const uint4*)p;
#pragma unroll
  for (int j = 0; j < 8; j++) v[j] += __bfloat162float(pk.h[j]);
}

// ---------------- merged init: conv0 (blocks 0..4095) + weight prep ----------------
template <int KT>
__device__ __forceinline__ void prep_conv_body(const float* __restrict__ w, __hip_bfloat16* __restrict__ wt,
                                               int co, float* l) {
  const float* wb = w + (size_t)co * 512 * KT;
  for (int i = threadIdx.x; i < 512 * KT; i += 512) l[i] = wb[i];
  __syncthreads();
  __hip_bfloat16* wo = wt + (size_t)co * 512 * KT;
  for (int i = threadIdx.x; i < 512 * KT; i += 512) {
    int kk = i >> 9, ci = i & 511;
    wo[i] = __float2bfloat16(l[ci * KT + kk]);
  }
}

template <int KD, int ND>
__device__ __forceinline__ void prep_mlp_body(const float* __restrict__ w, __hip_bfloat16* __restrict__ wt,
                                              int bidx, float* sbuf) {
  float(*tile)[33] = (float(*)[33])sbuf;
  int bx = bidx % (ND / 32);
  int by = bidx / (ND / 32);
  int tx = threadIdx.x & 31, ty = threadIdx.x >> 5;  // ty 0..15
#pragma unroll
  for (int i = 0; i < 32; i += 16)
    tile[ty + i][tx] = w[(size_t)(by * 32 + ty + i) * ND + bx * 32 + tx];
  __syncthreads();
#pragma unroll
  for (int i = 0; i < 32; i += 16)
    wt[(size_t)(bx * 32 + ty + i) * KD + by * 32 + tx] = __float2bfloat16(tile[tx][ty + i]);
}

__device__ __forceinline__ void conv0_body(const float* __restrict__ x, const float* __restrict__ w,
                                           const float* __restrict__ bias, const float* __restrict__ gw,
                                           const float* __restrict__ gb, __hip_bfloat16* __restrict__ out,
                                           int blk, float* smem) {
  float* xv = smem;
  float* tb = smem + 64;
  float* stats = smem + 4672;
  int b = blk / (T0 / 8);
  int t0 = (blk % (T0 / 8)) * 8;
  int tid = threadIdx.x;
  if (tid < 45) xv[tid] = x[(size_t)b * LIN + refl(t0 * 5 - 3 + tid, LIN)];
  __syncthreads();
  float wk[10];
#pragma unroll
  for (int k = 0; k < 10; k++) wk[k] = w[tid * 10 + k];
  float bs = bias[tid];
  float acc[8];
#pragma unroll
  for (int tt = 0; tt < 8; tt++) {
    float a = bs;
#pragma unroll
    for (int k = 0; k < 10; k++) a += xv[tt * 5 + k] * wk[k];
    acc[tt] = a;
    tb[tid * 9 + tt] = a;
  }
  __syncthreads();
  int wave = tid >> 6, lane = tid & 63;
  float s = 0.f, q = 0.f;
#pragma unroll
  for (int j = 0; j < 8; j++) {
    float v = tb[(lane * 8 + j) * 9 + wave];
    s += v; q += v * v;
  }
#pragma unroll
  for (int off = 32; off > 0; off >>= 1) {
    s += __shfl_xor(s, off, 64);
    q += __shfl_xor(q, off, 64);
  }
  if (lane == 0) {
    float mean = s * (1.f / NC);
    float var = fmaxf((q - s * s * (1.f / NC)) * (1.f / (NC - 1)), 0.f);
    stats[wave] = mean;
    stats[8 + wave] = rsqrtf(var + EPSF);
  }
  __syncthreads();
  float gwv = gw[tid], gbv = gb[tid];
#pragma unroll
  for (int tt = 0; tt < 8; tt++) {
    float y = (acc[tt] - stats[tt]) * stats[8 + tt] * gwv + gbv;
    out[((size_t)(b * T0 + t0 + tt)) * NC + tid] = __float2bfloat16(fmaxf(y, 0.f));
  }
}

__global__ __launch_bounds__(512) void k_init(const float* x, const float* c0w, const float* c0b,
                                              const float* n0w, const float* n0b, __hip_bfloat16* h0b,
                                              const float* c1w, const float* c2w, const float* c3w,
                                              const float* mw1, const float* mw2,
                                              __hip_bfloat16* wt1, __hip_bfloat16* wt2,
                                              __hip_bfloat16* wt3, __hip_bfloat16* wm1t,
                                              __hip_bfloat16* wm2t) {
  __shared__ float smem[4688];
  int b = blockIdx.x;
  if (b < 4096) conv0_body(x, c0w, c0b, n0w, n0b, h0b, b, smem);
  else if (b < 4608) prep_conv_body<8>(c1w, wt1, b - 4096, smem);
  else if (b < 5120) prep_conv_body<4>(c2w, wt2, b - 4608, smem);
  else if (b < 5632) prep_conv_body<4>(c3w, wt3, b - 5120, smem);
  else if (b < 6656) prep_mlp_body<512, 2048>(mw1, wm1t, b - 5632, smem);
  else prep_mlp_body<2048, 2048>(mw2, wm2t, b - 6656, smem);
}

// ---------------- GEMM F: 256x256 tile, 512 thr (8 waves 2Mx4N, per-wave 128x64),
// ring-4 K32-step pipeline with COUNTED vmcnt (T3+T4+T5). The R8 4-barrier version —
// measured 44.5-44.9us on conv1 across two runs (vs 48.6 gemmB, 57.5 1-barrier R10).
// Wins only on long pipelines (conv1 NS=32); mlp2 (NS=16) keeps gemmB-SK3.
template <int MODE, int TIN_, int TOUT_, int SS, int PP, int KK, int NN, int SPLITK, int MM>
__global__ __launch_bounds__(512, 2) void k_gemmF(const __hip_bfloat16* __restrict__ A,
                                                  const __hip_bfloat16* __restrict__ Bt,
                                                  __hip_bfloat16* __restrict__ Cp) {
  __shared__ __align__(16) __hip_bfloat16 sA[4][256 * 32];
  __shared__ __align__(16) __hip_bfloat16 sB[4][256 * 32];
  const int tid = threadIdx.x;
  const int lane = tid & 63;
  const int wave = tid >> 6;           // 0..7
  const int wm = wave >> 2, wn = wave & 3;
  constexpr int nt = NN / 256;
  constexpr int PS = (MM / 2048) * nt;
  constexpr int KBT = KK / 32;
  constexpr int NS = KBT / SPLITK;     // K32 steps per block
  const int blk = blockIdx.x;
  const int xs = blk & 7, sl = blk >> 3;
  const int sk = sl / PS, rem = sl % PS;
  const int row0 = ((rem / nt) * 8 + xs) * 256;
  const int col0 = (rem % nt) * 256;
  const int kb0 = sk * NS;
  const int cq = lane >> 4, cl = lane & 15;

  const char* aP[2];
  const char* bP[2];

  auto stageA = [&](int kb, int slot) {
    bool recalc = (kb == kb0) || (MODE == 1 && (kb & 15) == 0);
    if (recalc) {
#pragma unroll
      for (int rr = 0; rr < 2; rr++) {
        int c = rr * 512 + tid;
        int m = c >> 2, kc = c & 3;
        int kcs = kc ^ (m & 3);
        size_t ga;
        if (MODE == 0) {
          ga = (size_t)(row0 + m) * KK + kb * 32 + kcs * 8;
        } else {
          int r = row0 + m;
          int bb = r / TOUT_;
          int t = r - bb * TOUT_;
          int k = (kb * 32) >> 9;
          int ci = ((kb * 32) & 511) + kcs * 8;
          int gt = refl(t * SS - PP + k, TIN_);
          ga = (((size_t)(bb * TIN_ + gt)) << 9) + ci;
        }
        aP[rr] = (const char*)(A + ga);
      }
    }
#pragma unroll
    for (int rr = 0; rr < 2; rr++) {
      gld16((char*)&sA[slot][0] + (rr * 512 + tid) * 16, aP[rr]);
      aP[rr] += 64;
    }
  };

  auto stageB = [&](int slot) {
#pragma unroll
    for (int rr = 0; rr < 2; rr++) {
      gld16((char*)&sB[slot][0] + (rr * 512 + tid) * 16, bP[rr]);
      bP[rr] += 64;
    }
  };

#pragma unroll
  for (int rr = 0; rr < 2; rr++) {
    int c = rr * 512 + tid;
    int n = c >> 2, kc = c & 3;
    int kcs = kc ^ (n & 3);
    bP[rr] = (const char*)(Bt + (size_t)(col0 + n) * KK + kb0 * 32 + kcs * 8);
  }

  f32x4 acc[8][4];
  const f32x4 zz = {0.f, 0.f, 0.f, 0.f};
#pragma unroll
  for (int mi = 0; mi < 8; mi++)
#pragma unroll
    for (int ni = 0; ni < 4; ni++) acc[mi][ni] = zz;

  // prologue: stage steps 0,1,2 (slots 0,1,2); retire step 0's 4 loads (keep 8 in flight)
  stageA(kb0 + 0, 0); stageB(0);
  if (NS > 1) { stageA(kb0 + 1, 1); stageB(1); }
  if (NS > 2) { stageA(kb0 + 2, 2); stageB(2); }
  if (NS > 2)      { asm volatile("s_waitcnt vmcnt(8)" ::: "memory"); }
  else if (NS > 1) { asm volatile("s_waitcnt vmcnt(4)" ::: "memory"); }
  else             { asm volatile("s_waitcnt vmcnt(0)" ::: "memory"); }
  __builtin_amdgcn_s_barrier();

  const int p = cq ^ (cl & 3);
  for (int s = 0; s < NS; ++s) {
    const int slot = s & 3;
    const short* bA = (const short*)&sA[slot][0];
    const short* bB = (const short*)&sB[slot][0];
    bf16x8 bfr[4], af[4];

    // ---- phase A: read B + A rows 0-3; stage A of step s+3; 16 MFMA ----
#pragma unroll
    for (int ni = 0; ni < 4; ni++)
      bfr[ni] = *(const bf16x8*)(bB + (wn * 64 + ni * 16 + cl) * 32 + p * 8);
#pragma unroll
    for (int i = 0; i < 4; i++)
      af[i] = *(const bf16x8*)(bA + (wm * 128 + i * 16 + cl) * 32 + p * 8);
    if (s + 3 < NS) stageA(kb0 + s + 3, (s + 3) & 3);
    __builtin_amdgcn_s_barrier();
    asm volatile("s_waitcnt lgkmcnt(0)" ::: "memory");
    __builtin_amdgcn_s_setprio(1);
#pragma unroll
    for (int i = 0; i < 4; i++)
#pragma unroll
      for (int ni = 0; ni < 4; ni++)
        acc[i][ni] = __builtin_amdgcn_mfma_f32_16x16x32_bf16(af[i], bfr[ni], acc[i][ni], 0, 0, 0);
    __builtin_amdgcn_s_setprio(0);
    __builtin_amdgcn_s_barrier();

    // ---- phase B: read A rows 4-7; stage B of step s+3; counted drain for s+1; 16 MFMA ----
#pragma unroll
    for (int i = 0; i < 4; i++)
      af[i] = *(const bf16x8*)(bA + (wm * 128 + (4 + i) * 16 + cl) * 32 + p * 8);
    if (s + 3 < NS) stageB((s + 3) & 3);
    if (s + 1 < NS) {
      // outstanding = 4 x (#staged steps beyond s); retire step s+1 only (issued 3 phases ago)
      if (s + 3 < NS)      { asm volatile("s_waitcnt vmcnt(8)" ::: "memory"); }
      else if (s + 2 < NS) { asm volatile("s_waitcnt vmcnt(4)" ::: "memory"); }
      else                 { asm volatile("s_waitcnt vmcnt(0)" ::: "memory"); }
    }
    __builtin_amdgcn_s_barrier();
    asm volatile("s_waitcnt lgkmcnt(0)" ::: "memory");
    __builtin_amdgcn_s_setprio(1);
#pragma unroll
    for (int i = 0; i < 4; i++)
#pragma unroll
      for (int ni = 0; ni < 4; ni++)
        acc[4 + i][ni] = __builtin_amdgcn_mfma_f32_16x16x32_bf16(af[i], bfr[ni], acc[4 + i][ni], 0, 0, 0);
    __builtin_amdgcn_s_setprio(0);
    __builtin_amdgcn_s_barrier();
  }

#pragma unroll
  for (int mi = 0; mi < 8; mi++)
#pragma unroll
    for (int ni = 0; ni < 4; ni++)
#pragma unroll
      for (int r2 = 0; r2 < 4; r2++) {
        int row = row0 + wm * 128 + mi * 16 + cq * 4 + r2;
        int col = col0 + wn * 64 + ni * 16 + cl;
        Cp[(size_t)sk * MM * NN + (size_t)row * NN + col] = __float2bfloat16(acc[mi][ni][r2]);
      }
}

// ---------------- GEMM B: 128x128 tile (wave=64x64), BK=32, A dbuf + B chunk-dbuf (64K),
// SK, strength-reduced. 3 blocks/CU (LDS 48KB). Measured-best for conv2/mlp2.
template <int MODE, int TIN_, int TOUT_, int SS, int PP, int KK, int NN, int SPLITK, int MM>
__global__ __launch_bounds__(256) void k_gemmB(const __hip_bfloat16* __restrict__ A,
                                               const __hip_bfloat16* __restrict__ Bt,
                                               __hip_bfloat16* __restrict__ Cp) {
  __shared__ __align__(16) __hip_bfloat16 sA[2][128 * 32];
  __shared__ __align__(16) __hip_bfloat16 sB[2][2][128 * 32];  // [chunk-buf][sub][...]
  const int tid = threadIdx.x;
  const int lane = tid & 63;
  const int wave = tid >> 6;
  const int wm = wave >> 1, wn = wave & 1;
  constexpr int nt = NN / 128;
  constexpr int PS = (MM / 1024) * nt;
  constexpr int KBT = KK / 32;
  const int blk = blockIdx.x;
  const int xs = blk & 7, sl = blk >> 3;
  const int sk = sl / PS, rem = sl % PS;
  const int row0 = ((rem / nt) * 8 + xs) * 128;
  const int col0 = (rem % nt) * 128;
  const int kb0 = (sk * KBT) / SPLITK, kb1 = ((sk + 1) * KBT) / SPLITK;
  const int cq = lane >> 4, cl = lane & 15;

  const char* aP[2];
  const char* bP[2];

  auto stageA = [&](int kb, int buf) {
    bool recalc = (kb == kb0) || (MODE == 1 && (kb & 15) == 0);
    if (recalc) {
#pragma unroll
      for (int rr = 0; rr < 2; rr++) {
        int c = rr * 256 + tid;
        int m = c >> 2, kc = c & 3;
        int kcs = kc ^ (m & 3);
        size_t ga;
        if (MODE == 0) {
          ga = (size_t)(row0 + m) * KK + kb * 32 + kcs * 8;
        } else {
          int r = row0 + m;
          int bb = r / TOUT_;
          int t = r - bb * TOUT_;
          int k = (kb * 32) >> 9;
          int ci = ((kb * 32) & 511) + kcs * 8;
          int gt = refl(t * SS - PP + k, TIN_);
          ga = (((size_t)(bb * TIN_ + gt)) << 9) + ci;
        }
        aP[rr] = (const char*)(A + ga);
      }
    }
#pragma unroll
    for (int rr = 0; rr < 2; rr++) {
      gld16((char*)&sA[buf][0] + (rr * 256 + tid) * 16, aP[rr]);
      aP[rr] += 64;
    }
  };

  // Stages a full 64-K chunk (2 sub-tiles) into chunk-buf `buf`; advances bP by 128B.
  auto stageB = [&](int buf, bool doSub1) {
#pragma unroll
    for (int rr = 0; rr < 2; rr++) {
      gld16((char*)&sB[buf][0][0] + (rr * 256 + tid) * 16, bP[rr]);
      if (doSub1) gld16((char*)&sB[buf][1][0] + (rr * 256 + tid) * 16, bP[rr] + 64);
      bP[rr] += 128;
    }
  };

#pragma unroll
  for (int rr = 0; rr < 2; rr++) {
    int c = rr * 256 + tid;
    int n = c >> 2, kc = c & 3;
    int kcs = kc ^ (n & 3);
    bP[rr] = (const char*)(Bt + (size_t)(col0 + n) * KK + kb0 * 32 + kcs * 8);
  }

  f32x4 acc[4][4];
  const f32x4 zz = {0.f, 0.f, 0.f, 0.f};
#pragma unroll
  for (int mi = 0; mi < 4; mi++)
#pragma unroll
    for (int ni = 0; ni < 4; ni++) acc[mi][ni] = zz;

  stageA(kb0, 0);
  stageB(0, kb0 + 1 < kb1);

  const int p = cq ^ (cl & 3);
  for (int kb = kb0; kb < kb1; kb++) {
    const int jj = kb - kb0;
    __syncthreads();
    if (kb + 1 < kb1) stageA(kb + 1, (jj + 1) & 1);
    if (((jj & 1) == 0) && (kb + 2 < kb1)) stageB(((jj >> 1) + 1) & 1, kb + 3 < kb1);
    const short* bA = (const short*)&sA[jj & 1][0];
    const short* bB = (const short*)&sB[(jj >> 1) & 1][jj & 1][0];
    bf16x8 af[4], bfr[4];
#pragma unroll
    for (int mi = 0; mi < 4; mi++)
      af[mi] = *(const bf16x8*)(bA + (wm * 64 + mi * 16 + cl) * 32 + p * 8);
#pragma unroll
    for (int ni = 0; ni < 4; ni++)
      bfr[ni] = *(const bf16x8*)(bB + (wn * 64 + ni * 16 + cl) * 32 + p * 8);
#pragma unroll
    for (int mi = 0; mi < 4; mi++)
#pragma unroll
      for (int ni = 0; ni < 4; ni++)
        acc[mi][ni] = __builtin_amdgcn_mfma_f32_16x16x32_bf16(af[mi], bfr[ni], acc[mi][ni], 0, 0, 0);
  }

#pragma unroll
  for (int mi = 0; mi < 4; mi++)
#pragma unroll
    for (int ni = 0; ni < 4; ni++)
#pragma unroll
      for (int r2 = 0; r2 < 4; r2++) {
        int row = row0 + wm * 64 + mi * 16 + cq * 4 + r2;
        int col = col0 + wn * 64 + ni * 16 + cl;
        Cp[(size_t)sk * MM * NN + (size_t)row * NN + col] = __float2bfloat16(acc[mi][ni][r2]);
      }
}

// ---------------- GEMM C: 64x128 tile (conv3, mlp1), A dbuf + B chunk-dbuf, 4 blocks/CU --
template <int MODE, int TIN_, int TOUT_, int SS, int PP, int KK, int NN, int EPI, int SPLITK, int MM>
__global__ __launch_bounds__(256, 4) void k_gemmC(const __hip_bfloat16* __restrict__ A,
                                                  const __hip_bfloat16* __restrict__ Bt,
                                                  const float* __restrict__ bias,
                                                  __hip_bfloat16* __restrict__ Cout) {
  __shared__ __align__(16) __hip_bfloat16 sA[2][64 * 32];
  __shared__ __align__(16) __hip_bfloat16 sB[2][2][128 * 32];  // [chunk-buf][sub][...]
  const int tid = threadIdx.x;
  const int lane = tid & 63;
  const int wave = tid >> 6;
  const int wm = wave >> 1, wn = wave & 1;
  constexpr int nt = NN / 128;
  constexpr int PS = (MM / 512) * nt;
  constexpr int KBT = KK / 32;
  const int blk = blockIdx.x;
  const int xs = blk & 7, sl = blk >> 3;
  const int sk = sl / PS, rem = sl % PS;
  const int row0 = ((rem / nt) * 8 + xs) * 64;
  const int col0 = (rem % nt) * 128;
  const int kb0 = (sk * KBT) / SPLITK, kb1 = ((sk + 1) * KBT) / SPLITK;
  const int cq = lane >> 4, cl = lane & 15;

  const char* aP;
  const char* bP[2];

  auto stageA = [&](int kb, int buf) {
    bool recalc = (kb == kb0) || (MODE == 1 && (kb & 15) == 0);
    if (recalc) {
      int m = tid >> 2, kc = tid & 3;
      int kcs = kc ^ (m & 3);
      size_t ga;
      if (MODE == 0) {
        ga = (size_t)(row0 + m) * KK + kb * 32 + kcs * 8;
      } else {
        int r = row0 + m;
        int bb = r / TOUT_;
        int t = r - bb * TOUT_;
        int k = (kb * 32) >> 9;
        int ci = ((kb * 32) & 511) + kcs * 8;
        int gt = refl(t * SS - PP + k, TIN_);
        ga = (((size_t)(bb * TIN_ + gt)) << 9) + ci;
      }
      aP = (const char*)(A + ga);
    }
    gld16((char*)&sA[buf][0] + tid * 16, aP);
    aP += 64;
  };

  auto stageB = [&](int buf, bool doSub1) {
#pragma unroll
    for (int rr = 0; rr < 2; rr++) {
      gld16((char*)&sB[buf][0][0] + (rr * 256 + tid) * 16, bP[rr]);
      if (doSub1) gld16((char*)&sB[buf][1][0] + (rr * 256 + tid) * 16, bP[rr] + 64);
      bP[rr] += 128;
    }
  };

#pragma unroll
  for (int rr = 0; rr < 2; rr++) {
    int c = rr * 256 + tid;
    int n = c >> 2, kc = c & 3;
    int kcs = kc ^ (n & 3);
    bP[rr] = (const char*)(Bt + (size_t)(col0 + n) * KK + kb0 * 32 + kcs * 8);
  }

  f32x4 acc[2][4];
  const f32x4 zz = {0.f, 0.f, 0.f, 0.f};
#pragma unroll
  for (int mi = 0; mi < 2; mi++)
#pragma unroll
    for (int ni = 0; ni < 4; ni++) acc[mi][ni] = zz;

  stageA(kb0, 0);
  stageB(0, kb0 + 1 < kb1);

  const int p = cq ^ (cl & 3);
  for (int kb = kb0; kb < kb1; kb++) {
    const int jj = kb - kb0;
    __syncthreads();
    if (kb + 1 < kb1) stageA(kb + 1, (jj + 1) & 1);
    if (((jj & 1) == 0) && (kb + 2 < kb1)) stageB(((jj >> 1) + 1) & 1, kb + 3 < kb1);
    const short* bA = (const short*)&sA[jj & 1][0];
    const short* bB = (const short*)&sB[(jj >> 1) & 1][jj & 1][0];
    bf16x8 af[2], bfr[4];
#pragma unroll
    for (int mi = 0; mi < 2; mi++)
      af[mi] = *(const bf16x8*)(bA + (wm * 32 + mi * 16 + cl) * 32 + p * 8);
#pragma unroll
    for (int ni = 0; ni < 4; ni++)
      bfr[ni] = *(const bf16x8*)(bB + (wn * 64 + ni * 16 + cl) * 32 + p * 8);
#pragma unroll
    for (int mi = 0; mi < 2; mi++)
#pragma unroll
      for (int ni = 0; ni < 4; ni++)
        acc[mi][ni] = __builtin_amdgcn_mfma_f32_16x16x32_bf16(af[mi], bfr[ni], acc[mi][ni], 0, 0, 0);
  }

#pragma unroll
  for (int mi = 0; mi < 2; mi++)
#pragma unroll
    for (int ni = 0; ni < 4; ni++)
#pragma unroll
      for (int r2 = 0; r2 < 4; r2++) {
        int row = row0 + wm * 32 + mi * 16 + cq * 4 + r2;
        int col = col0 + wn * 64 + ni * 16 + cl;
        float v = acc[mi][ni][r2];
        if (EPI == 1) {
          v += bias[col];
          v = 0.5f * v * (1.f + erff(v * 0.70710678118654752f));
          Cout[(size_t)row * NN + col] = __float2bfloat16(v);
        } else {
          Cout[(size_t)sk * MM * NN + (size_t)row * NN + col] = __float2bfloat16(v);
        }
      }
}

// ---------------- ChannelNorm (+conv bias, sum NS bf16 split-K partials) + ReLU -> bf16
template <int NS>
__global__ __launch_bounds__(512) void k_cnorm(const __hip_bfloat16* __restrict__ g,
                                               const float* __restrict__ cb,
                                               const float* __restrict__ gw, const float* __restrict__ gb,
                                               __hip_bfloat16* __restrict__ out, size_t stride) {
  int wave = threadIdx.x >> 6, lane = threadIdx.x & 63;
  size_t row = (size_t)blockIdx.x * 8 + wave;
  float v[8];
  {
    float4 c0 = *(const float4*)(cb + lane * 8), c1 = *(const float4*)(cb + lane * 8 + 4);
    v[0] = c0.x; v[1] = c0.y; v[2] = c0.z; v[3] = c0.w;
    v[4] = c1.x; v[5] = c1.y; v[6] = c1.z; v[7] = c1.w;
  }
#pragma unroll
  for (int s = 0; s < NS; s++) add_bf8(g + s * stride + row * NC + lane * 8, v);
  float s = 0.f, q = 0.f;
#pragma unroll
  for (int j = 0; j < 8; j++) { s += v[j]; q += v[j] * v[j]; }
#pragma unroll
  for (int off = 32; off > 0; off >>= 1) {
    s += __shfl_xor(s, off, 64);
    q += __shfl_xor(q, off, 64);
  }
  float mean = s * (1.f / NC);
  float var = fmaxf((q - s * s * (1.f / NC)) * (1.f / (NC - 1)), 0.f);
  float rstd = rsqrtf(var + EPSF);
  float4 w0 = *(const float4*)(gw + lane * 8), w1 = *(const float4*)(gw + lane * 8 + 4);
  float4 b0 = *(const float4*)(gb + lane * 8), b1 = *(const float4*)(gb + lane * 8 + 4);
  float gwv[8] = {w0.x, w0.y, w0.z, w0.w, w1.x, w1.y, w1.z, w1.w};
  float gbv[8] = {b0.x, b0.y, b0.z, b0.w, b1.x, b1.y, b1.z, b1.w};
  union { __hip_bfloat16 h[8]; uint4 u; } pk;
#pragma unroll
  for (int j = 0; j < 8; j++)
    pk.h[j] = __float2bfloat16(fmaxf((v[j] - mean) * rstd * gwv[j] + gbv[j], 0.f));
  *(uint4*)(out + row * NC + lane * 8) = pk.u;
}

// ---------------- fused head: sum NS bf16 partials + bias + GELU, dot w3, sigmoid ----
template <int NS>
__global__ __launch_bounds__(256) void k_head(const __hip_bfloat16* __restrict__ g,
                                              const float* __restrict__ b2,
                                              const float* __restrict__ w3, const float* __restrict__ b3,
                                              float* __restrict__ imp) {
  __shared__ float red[4];
  int row = blockIdx.x, tid = threadIdx.x;
  int c = tid * 8;
  float v[8];
  {
    float4 x0 = *(const float4*)(b2 + c), x1 = *(const float4*)(b2 + c + 4);
    v[0] = x0.x; v[1] = x0.y; v[2] = x0.z; v[3] = x0.w;
    v[4] = x1.x; v[5] = x1.y; v[6] = x1.z; v[7] = x1.w;
  }
#pragma unroll
  for (int s = 0; s < NS; s++) add_bf8(g + (size_t)s * (2048 * DM) + (size_t)row * DM + c, v);
  float a = 0.f;
  float4 w0 = *(const float4*)(w3 + c), w1 = *(const float4*)(w3 + c + 4);
  float wv[8] = {w0.x, w0.y, w0.z, w0.w, w1.x, w1.y, w1.z, w1.w};
#pragma unroll
  for (int j = 0; j < 8; j++) {
    float z = 0.5f * v[j] * (1.f + erff(v[j] * 0.70710678118654752f));
    a += z * wv[j];
  }
#pragma unroll
  for (int off = 32; off > 0; off >>= 1) a += __shfl_down(a, off, 64);
  int lane = tid & 63, wid = tid >> 6;
  if (lane == 0) red[wid] = a;
  __syncthreads();
  if (tid == 0) {
    float s = red[0] + red[1] + red[2] + red[3] + b3[0];
    imp[row] = 1.f / (1.f + expf(-s)) + TEMPF;
  }
}

__device__ __forceinline__ float dfun(float cv, int n) {
  float d = fmaxf(cv - (float)n, 0.f);
  if (n < TN - 1) d = fminf(d, 1.f);
  return d;
}

// ---------------- fused cumsum + pool + final ChannelNorm + ReLU, write [B][C][TN] ----
// R12 fix (−22us e2e): nonzero support of wt is a contiguous t-range (cumsum monotone),
// found via per-wave ballot + 8-entry min/max; loop only [tmin,tmax] (~2-4 iters vs 512
// serial ~120cy LDS broadcasts). if(w!=0) kept -> FP sum over nonzero terms unchanged.
__global__ __launch_bounds__(512) void k_poolfinal(const __hip_bfloat16* __restrict__ f,
                                                   const float* __restrict__ imp,
                                                   const float* __restrict__ gw, const float* __restrict__ gb,
                                                   float* __restrict__ out) {
  __shared__ float wt[T3];
  __shared__ float wsum[8];
  __shared__ float red[16];
  __shared__ int rmin[8], rmax[8];
  int b = blockIdx.x / TN, n = blockIdx.x % TN;
  int tid = threadIdx.x, wave = tid >> 6, lane = tid & 63;
  float own = imp[b * T3 + tid];
  float s = own;
#pragma unroll
  for (int off = 1; off < 64; off <<= 1) {
    float t = __shfl_up(s, off, 64);
    if (lane >= off) s += t;
  }
  if (lane == 63) wsum[wave] = s;
  __syncthreads();
  float prefix = 0.f, total = 0.f;
#pragma unroll
  for (int w = 0; w < 8; w++) {
    float ws_ = wsum[w];
    total += ws_;
    if (w < wave) prefix += ws_;
  }
  float scale = (float)TN / total;
  float incl = (prefix + s) * scale;
  float excl = (prefix + s - own) * scale;
  float myw = dfun(incl, n) - dfun(excl, n);
  wt[tid] = myw;
  // locate the contiguous nonzero t-range
  unsigned long long m = __ballot(myw != 0.f);
  if (lane == 0) {
    rmin[wave] = m ? (wave * 64 + __ffsll(m) - 1) : T3;
    rmax[wave] = m ? (wave * 64 + 63 - __clzll(m)) : -1;
  }
  __syncthreads();
  int tmin = T3, tmax = -1;
#pragma unroll
  for (int w = 0; w < 8; w++) {
    tmin = min(tmin, rmin[w]);
    tmax = max(tmax, rmax[w]);
  }
  float acc = 0.f;
  for (int t = tmin; t <= tmax; t++) {
    float w = wt[t];
    if (w != 0.f) acc += w * __bfloat162float(f[((size_t)b * T3 + t) * NC + tid]);
  }
  float sv = acc, q = acc * acc;
  blk_sum2_512(sv, q, red);
  float mean = sv * (1.f / NC);
  float var = fmaxf((q - sv * sv * (1.f / NC)) * (1.f / (NC - 1)), 0.f);
  float y = (acc - mean) * rsqrtf(var + EPSF) * gw[tid] + gb[tid];
  out[((size_t)b * NC + tid) * TN + n] = fmaxf(y, 0.f);
}

extern "C" void kernel_launch(void* const* d_in, const int* in_sizes, int n_in,
                              void* d_out, int out_size, void* d_ws, size_t ws_size,
                              hipStream_t stream) {
  const float* x   = (const float*)d_in[0];
  const float* c0w = (const float*)d_in[1];  const float* c0b = (const float*)d_in[2];
  const float* c1w = (const float*)d_in[3];  const float* c1b = (const float*)d_in[4];
  const float* c2w = (const float*)d_in[5];  const float* c2b = (const float*)d_in[6];
  const float* c3w = (const float*)d_in[7];  const float* c3b = (const float*)d_in[8];
  const float* mw1 = (const float*)d_in[9];  const float* mb1 = (const float*)d_in[10];
  const float* mw2 = (const float*)d_in[11]; const float* mb2 = (const float*)d_in[12];
  const float* mw3 = (const float*)d_in[13]; const float* mb3 = (const float*)d_in[14];
  const float* n0w = (const float*)d_in[15]; const float* n0b = (const float*)d_in[16];
  const float* n1w = (const float*)d_in[17]; const float* n1b = (const float*)d_in[18];
  const float* n2w = (const float*)d_in[19]; const float* n2b = (const float*)d_in[20];
  const float* n3w = (const float*)d_in[21]; const float* n3b = (const float*)d_in[22];
  const float* n4w = (const float*)d_in[23]; const float* n4b = (const float*)d_in[24];

  char* base = (char*)d_ws;
  // Workspace map (MiB). Peak 82 MiB (R8 layout).
  __hip_bfloat16* h0b  = (__hip_bfloat16*)(base);                     // [0,32): conv0 out; dead after conv1-gemm
  __hip_bfloat16* h1b  = (__hip_bfloat16*)(base);                     // reuse [0,8)
  __hip_bfloat16* h2b  = (__hip_bfloat16*)(base + (8u << 20));        // reuse [8,12)
  __hip_bfloat16* h3b  = (__hip_bfloat16*)(base + (12u << 20));       // reuse [12,14)
  __hip_bfloat16* z1b  = (__hip_bfloat16*)(base + (14u << 20));       // reuse [14,22)
  float*          imp  = (float*)(base + (22u << 20));                // reuse [22,+8K)
  __hip_bfloat16* g    = (__hip_bfloat16*)(base + (32u << 20));       // [32,64): bf16 split-K partials
  __hip_bfloat16* wm1t = (__hip_bfloat16*)(base + (64u << 20));       // [64,66)
  __hip_bfloat16* wt2  = (__hip_bfloat16*)(base + (66u << 20));       // [66,68)
  __hip_bfloat16* wt3  = (__hip_bfloat16*)(base + (68u << 20));       // [68,70)
  __hip_bfloat16* wt1  = (__hip_bfloat16*)(base + (70u << 20));       // [70,74)
  __hip_bfloat16* wm2t = (__hip_bfloat16*)(base + (74u << 20));       // [74,82)
  float* outp = (float*)d_out;

  k_init<<<4096 + 6656, 512, 0, stream>>>(x, c0w, c0b, n0w, n0b, h0b,
                                          c1w, c2w, c3w, mw1, mw2, wt1, wt2, wt3, wm1t, wm2t);

  // conv1: 256x256 ring-4 counted-vmcnt gemmF (measured 44.5-44.9us, R8/R9), SK4 -> 256 blocks.
  k_gemmF<1, 8192, 2048, 4, 2, 4096, 512, 4, 8192><<<256, 512, 0, stream>>>(h0b, wt1, g);
  k_cnorm<4><<<8192 / 8, 512, 0, stream>>>(g, c1b, n1w, n1b, h1b, (size_t)8192 * 512);
  // conv2: 128x128, SK6 -> 768 blocks (3/CU)
  k_gemmB<1, 2048, 1024, 2, 1, 2048, 512, 6, 4096><<<768, 256, 0, stream>>>(h1b, wt2, g);
  k_cnorm<6><<<4096 / 8, 512, 0, stream>>>(g, c2b, n2w, n2b, h2b, (size_t)4096 * 512);
  // conv3: 64x128, SK6 -> 768 blocks
  k_gemmC<1, 1024, 512, 2, 1, 2048, 512, 0, 6, 2048><<<768, 256, 0, stream>>>(h2b, wt3, c3b, g);
  k_cnorm<6><<<2048 / 8, 512, 0, stream>>>(g, c3b, n3w, n3b, h3b, (size_t)2048 * 512);
  // mlp1: 64x128, EPI=GELU -> 512 blocks
  k_gemmC<0, 0, 1, 0, 0, 512, 2048, 1, 1, 2048><<<512, 256, 0, stream>>>(h3b, wm1t, mb1, z1b);
  // mlp2: 128x128, SK3 -> 768 blocks (gemmF measured ~5us slower here; keep gemmB)
  k_gemmB<0, 0, 1, 0, 0, 2048, 2048, 3, 2048><<<768, 256, 0, stream>>>(z1b, wm2t, g);

  k_head<3><<<NB * T3, 256, 0, stream>>>(g, mb2, mw3, mb3, imp);
  k_poolfinal<<<NB * TN, 512, 0, stream>>>(h3b, imp, n4w, n4b, outp);
}

// Round 16
// 291.768 us; speedup vs baseline: 1.5755x; 1.0009x over previous
//
#include <hip/hip_runtime.h>
#include <hip/hip_bf16.h>
#include <math.h>

#define NB 4
#define LIN 40960
#define NC 512
#define T0 8192
#define T1 2048
#define T2 1024
#define T3 512
#define TN 256
#define DM 2048
#define EPSF 1e-5f
#define TEMPF 1e-5f

typedef __attribute__((ext_vector_type(8))) short bf16x8;
typedef __attribute__((ext_vector_type(4))) float f32x4;

__device__ __forceinline__ int refl(int t, int T) {
  if (t < 0) t = -t;
  if (t >= T) t = 2 * T - 2 - t;
  return t;
}

__device__ __forceinline__ void gld16(void* lds, const void* g) {
  __builtin_amdgcn_global_load_lds((const __attribute__((address_space(1))) unsigned int*)g,
                                   (__attribute__((address_space(3))) unsigned int*)lds, 16, 0, 0);
}

__device__ __forceinline__ void blk_sum2_512(float& a, float& b, float* scratch) {
#pragma unroll
  for (int off = 32; off > 0; off >>= 1) {
    a += __shfl_down(a, off, 64);
    b += __shfl_down(b, off, 64);
  }
  int lane = threadIdx.x & 63, wid = threadIdx.x >> 6;
  __syncthreads();
  if (lane == 0) { scratch[wid] = a; scratch[8 + wid] = b; }
  __syncthreads();
  float sa = 0.f, sb = 0.f;
#pragma unroll
  for (int i = 0; i < 8; i++) { sa += scratch[i]; sb += scratch[8 + i]; }
  a = sa; b = sb;
}

__device__ __forceinline__ void add_bf8(const __hip_bfloat16* p, float* v) {
  union { uint4 u; __hip_bfloat16 h[8]; } pk;
  pk.u = *(const uint4*)p;
#pragma unroll
  for (int j = 0; j < 8; j++) v[j] += __bfloat162float(pk.h[j]);
}

// ---------------- merged init: conv0 (blocks 0..4095) + weight prep ----------------
template <int KT>
__device__ __forceinline__ void prep_conv_body(const float* __restrict__ w, __hip_bfloat16* __restrict__ wt,
                                               int co, float* l) {
  const float* wb = w + (size_t)co * 512 * KT;
  for (int i = threadIdx.x; i < 512 * KT; i += 512) l[i] = wb[i];
  __syncthreads();
  __hip_bfloat16* wo = wt + (size_t)co * 512 * KT;
  for (int i = threadIdx.x; i < 512 * KT; i += 512) {
    int kk = i >> 9, ci = i & 511;
    wo[i] = __float2bfloat16(l[ci * KT + kk]);
  }
}

template <int KD, int ND>
__device__ __forceinline__ void prep_mlp_body(const float* __restrict__ w, __hip_bfloat16* __restrict__ wt,
                                              int bidx, float* sbuf) {
  float(*tile)[33] = (float(*)[33])sbuf;
  int bx = bidx % (ND / 32);
  int by = bidx / (ND / 32);
  int tx = threadIdx.x & 31, ty = threadIdx.x >> 5;  // ty 0..15
#pragma unroll
  for (int i = 0; i < 32; i += 16)
    tile[ty + i][tx] = w[(size_t)(by * 32 + ty + i) * ND + bx * 32 + tx];
  __syncthreads();
#pragma unroll
  for (int i = 0; i < 32; i += 16)
    wt[(size_t)(bx * 32 + ty + i) * KD + by * 32 + tx] = __float2bfloat16(tile[tx][ty + i]);
}

__device__ __forceinline__ void conv0_body(const float* __restrict__ x, const float* __restrict__ w,
                                           const float* __restrict__ bias, const float* __restrict__ gw,
                                           const float* __restrict__ gb, __hip_bfloat16* __restrict__ out,
                                           int blk, float* smem) {
  float* xv = smem;
  float* tb = smem + 64;
  float* stats = smem + 4672;
  int b = blk / (T0 / 8);
  int t0 = (blk % (T0 / 8)) * 8;
  int tid = threadIdx.x;
  if (tid < 45) xv[tid] = x[(size_t)b * LIN + refl(t0 * 5 - 3 + tid, LIN)];
  __syncthreads();
  float wk[10];
#pragma unroll
  for (int k = 0; k < 10; k++) wk[k] = w[tid * 10 + k];
  float bs = bias[tid];
  float acc[8];
#pragma unroll
  for (int tt = 0; tt < 8; tt++) {
    float a = bs;
#pragma unroll
    for (int k = 0; k < 10; k++) a += xv[tt * 5 + k] * wk[k];
    acc[tt] = a;
    tb[tid * 9 + tt] = a;
  }
  __syncthreads();
  int wave = tid >> 6, lane = tid & 63;
  float s = 0.f, q = 0.f;
#pragma unroll
  for (int j = 0; j < 8; j++) {
    float v = tb[(lane * 8 + j) * 9 + wave];
    s += v; q += v * v;
  }
#pragma unroll
  for (int off = 32; off > 0; off >>= 1) {
    s += __shfl_xor(s, off, 64);
    q += __shfl_xor(q, off, 64);
  }
  if (lane == 0) {
    float mean = s * (1.f / NC);
    float var = fmaxf((q - s * s * (1.f / NC)) * (1.f / (NC - 1)), 0.f);
    stats[wave] = mean;
    stats[8 + wave] = rsqrtf(var + EPSF);
  }
  __syncthreads();
  float gwv = gw[tid], gbv = gb[tid];
#pragma unroll
  for (int tt = 0; tt < 8; tt++) {
    float y = (acc[tt] - stats[tt]) * stats[8 + tt] * gwv + gbv;
    out[((size_t)(b * T0 + t0 + tt)) * NC + tid] = __float2bfloat16(fmaxf(y, 0.f));
  }
}

__global__ __launch_bounds__(512) void k_init(const float* x, const float* c0w, const float* c0b,
                                              const float* n0w, const float* n0b, __hip_bfloat16* h0b,
                                              const float* c1w, const float* c2w, const float* c3w,
                                              const float* mw1, const float* mw2,
                                              __hip_bfloat16* wt1, __hip_bfloat16* wt2,
                                              __hip_bfloat16* wt3, __hip_bfloat16* wm1t,
                                              __hip_bfloat16* wm2t) {
  __shared__ float smem[4688];
  int b = blockIdx.x;
  if (b < 4096) conv0_body(x, c0w, c0b, n0w, n0b, h0b, b, smem);
  else if (b < 4608) prep_conv_body<8>(c1w, wt1, b - 4096, smem);
  else if (b < 5120) prep_conv_body<4>(c2w, wt2, b - 4608, smem);
  else if (b < 5632) prep_conv_body<4>(c3w, wt3, b - 5120, smem);
  else if (b < 6656) prep_mlp_body<512, 2048>(mw1, wm1t, b - 5632, smem);
  else prep_mlp_body<2048, 2048>(mw2, wm2t, b - 6656, smem);
}

// ---------------- GEMM F: 256x256 tile, 512 thr (8 waves 2Mx4N, per-wave 128x64),
// ring-4 K32-step pipeline with COUNTED vmcnt (T3+T4+T5). The R8 4-barrier version —
// measured 44.5-44.9us on conv1 across three runs (vs 48.6 gemmB, 57.5 1-barrier R10).
// Wins only on long pipelines (conv1 NS=32); mlp2 (NS=16) keeps gemmB-SK3.
template <int MODE, int TIN_, int TOUT_, int SS, int PP, int KK, int NN, int SPLITK, int MM>
__global__ __launch_bounds__(512, 2) void k_gemmF(const __hip_bfloat16* __restrict__ A,
                                                  const __hip_bfloat16* __restrict__ Bt,
                                                  __hip_bfloat16* __restrict__ Cp) {
  __shared__ __align__(16) __hip_bfloat16 sA[4][256 * 32];
  __shared__ __align__(16) __hip_bfloat16 sB[4][256 * 32];
  const int tid = threadIdx.x;
  const int lane = tid & 63;
  const int wave = tid >> 6;           // 0..7
  const int wm = wave >> 2, wn = wave & 3;
  constexpr int nt = NN / 256;
  constexpr int PS = (MM / 2048) * nt;
  constexpr int KBT = KK / 32;
  constexpr int NS = KBT / SPLITK;     // K32 steps per block
  const int blk = blockIdx.x;
  const int xs = blk & 7, sl = blk >> 3;
  const int sk = sl / PS, rem = sl % PS;
  const int row0 = ((rem / nt) * 8 + xs) * 256;
  const int col0 = (rem % nt) * 256;
  const int kb0 = sk * NS;
  const int cq = lane >> 4, cl = lane & 15;

  const char* aP[2];
  const char* bP[2];

  auto stageA = [&](int kb, int slot) {
    bool recalc = (kb == kb0) || (MODE == 1 && (kb & 15) == 0);
    if (recalc) {
#pragma unroll
      for (int rr = 0; rr < 2; rr++) {
        int c = rr * 512 + tid;
        int m = c >> 2, kc = c & 3;
        int kcs = kc ^ (m & 3);
        size_t ga;
        if (MODE == 0) {
          ga = (size_t)(row0 + m) * KK + kb * 32 + kcs * 8;
        } else {
          int r = row0 + m;
          int bb = r / TOUT_;
          int t = r - bb * TOUT_;
          int k = (kb * 32) >> 9;
          int ci = ((kb * 32) & 511) + kcs * 8;
          int gt = refl(t * SS - PP + k, TIN_);
          ga = (((size_t)(bb * TIN_ + gt)) << 9) + ci;
        }
        aP[rr] = (const char*)(A + ga);
      }
    }
#pragma unroll
    for (int rr = 0; rr < 2; rr++) {
      gld16((char*)&sA[slot][0] + (rr * 512 + tid) * 16, aP[rr]);
      aP[rr] += 64;
    }
  };

  auto stageB = [&](int slot) {
#pragma unroll
    for (int rr = 0; rr < 2; rr++) {
      gld16((char*)&sB[slot][0] + (rr * 512 + tid) * 16, bP[rr]);
      bP[rr] += 64;
    }
  };

#pragma unroll
  for (int rr = 0; rr < 2; rr++) {
    int c = rr * 512 + tid;
    int n = c >> 2, kc = c & 3;
    int kcs = kc ^ (n & 3);
    bP[rr] = (const char*)(Bt + (size_t)(col0 + n) * KK + kb0 * 32 + kcs * 8);
  }

  f32x4 acc[8][4];
  const f32x4 zz = {0.f, 0.f, 0.f, 0.f};
#pragma unroll
  for (int mi = 0; mi < 8; mi++)
#pragma unroll
    for (int ni = 0; ni < 4; ni++) acc[mi][ni] = zz;

  // prologue: stage steps 0,1,2 (slots 0,1,2); retire step 0's 4 loads (keep 8 in flight)
  stageA(kb0 + 0, 0); stageB(0);
  if (NS > 1) { stageA(kb0 + 1, 1); stageB(1); }
  if (NS > 2) { stageA(kb0 + 2, 2); stageB(2); }
  if (NS > 2)      { asm volatile("s_waitcnt vmcnt(8)" ::: "memory"); }
  else if (NS > 1) { asm volatile("s_waitcnt vmcnt(4)" ::: "memory"); }
  else             { asm volatile("s_waitcnt vmcnt(0)" ::: "memory"); }
  __builtin_amdgcn_s_barrier();

  const int p = cq ^ (cl & 3);
  for (int s = 0; s < NS; ++s) {
    const int slot = s & 3;
    const short* bA = (const short*)&sA[slot][0];
    const short* bB = (const short*)&sB[slot][0];
    bf16x8 bfr[4], af[4];

    // ---- phase A: read B + A rows 0-3; stage A of step s+3; 16 MFMA ----
#pragma unroll
    for (int ni = 0; ni < 4; ni++)
      bfr[ni] = *(const bf16x8*)(bB + (wn * 64 + ni * 16 + cl) * 32 + p * 8);
#pragma unroll
    for (int i = 0; i < 4; i++)
      af[i] = *(const bf16x8*)(bA + (wm * 128 + i * 16 + cl) * 32 + p * 8);
    if (s + 3 < NS) stageA(kb0 + s + 3, (s + 3) & 3);
    __builtin_amdgcn_s_barrier();
    asm volatile("s_waitcnt lgkmcnt(0)" ::: "memory");
    __builtin_amdgcn_s_setprio(1);
#pragma unroll
    for (int i = 0; i < 4; i++)
#pragma unroll
      for (int ni = 0; ni < 4; ni++)
        acc[i][ni] = __builtin_amdgcn_mfma_f32_16x16x32_bf16(af[i], bfr[ni], acc[i][ni], 0, 0, 0);
    __builtin_amdgcn_s_setprio(0);
    __builtin_amdgcn_s_barrier();

    // ---- phase B: read A rows 4-7; stage B of step s+3; counted drain for s+1; 16 MFMA ----
#pragma unroll
    for (int i = 0; i < 4; i++)
      af[i] = *(const bf16x8*)(bA + (wm * 128 + (4 + i) * 16 + cl) * 32 + p * 8);
    if (s + 3 < NS) stageB((s + 3) & 3);
    if (s + 1 < NS) {
      // outstanding = 4 x (#staged steps beyond s); retire step s+1 only (issued 3 phases ago)
      if (s + 3 < NS)      { asm volatile("s_waitcnt vmcnt(8)" ::: "memory"); }
      else if (s + 2 < NS) { asm volatile("s_waitcnt vmcnt(4)" ::: "memory"); }
      else                 { asm volatile("s_waitcnt vmcnt(0)" ::: "memory"); }
    }
    __builtin_amdgcn_s_barrier();
    asm volatile("s_waitcnt lgkmcnt(0)" ::: "memory");
    __builtin_amdgcn_s_setprio(1);
#pragma unroll
    for (int i = 0; i < 4; i++)
#pragma unroll
      for (int ni = 0; ni < 4; ni++)
        acc[4 + i][ni] = __builtin_amdgcn_mfma_f32_16x16x32_bf16(af[i], bfr[ni], acc[4 + i][ni], 0, 0, 0);
    __builtin_amdgcn_s_setprio(0);
    __builtin_amdgcn_s_barrier();
  }

#pragma unroll
  for (int mi = 0; mi < 8; mi++)
#pragma unroll
    for (int ni = 0; ni < 4; ni++)
#pragma unroll
      for (int r2 = 0; r2 < 4; r2++) {
        int row = row0 + wm * 128 + mi * 16 + cq * 4 + r2;
        int col = col0 + wn * 64 + ni * 16 + cl;
        Cp[(size_t)sk * MM * NN + (size_t)row * NN + col] = __float2bfloat16(acc[mi][ni][r2]);
      }
}

// ---------------- GEMM B: 128x128 tile (wave=64x64), BK=32, A dbuf + B chunk-dbuf (64K),
// SK, strength-reduced. 3 blocks/CU (LDS 48KB). Measured-best for conv2/mlp2.
template <int MODE, int TIN_, int TOUT_, int SS, int PP, int KK, int NN, int SPLITK, int MM>
__global__ __launch_bounds__(256) void k_gemmB(const __hip_bfloat16* __restrict__ A,
                                               const __hip_bfloat16* __restrict__ Bt,
                                               __hip_bfloat16* __restrict__ Cp) {
  __shared__ __align__(16) __hip_bfloat16 sA[2][128 * 32];
  __shared__ __align__(16) __hip_bfloat16 sB[2][2][128 * 32];  // [chunk-buf][sub][...]
  const int tid = threadIdx.x;
  const int lane = tid & 63;
  const int wave = tid >> 6;
  const int wm = wave >> 1, wn = wave & 1;
  constexpr int nt = NN / 128;
  constexpr int PS = (MM / 1024) * nt;
  constexpr int KBT = KK / 32;
  const int blk = blockIdx.x;
  const int xs = blk & 7, sl = blk >> 3;
  const int sk = sl / PS, rem = sl % PS;
  const int row0 = ((rem / nt) * 8 + xs) * 128;
  const int col0 = (rem % nt) * 128;
  const int kb0 = (sk * KBT) / SPLITK, kb1 = ((sk + 1) * KBT) / SPLITK;
  const int cq = lane >> 4, cl = lane & 15;

  const char* aP[2];
  const char* bP[2];

  auto stageA = [&](int kb, int buf) {
    bool recalc = (kb == kb0) || (MODE == 1 && (kb & 15) == 0);
    if (recalc) {
#pragma unroll
      for (int rr = 0; rr < 2; rr++) {
        int c = rr * 256 + tid;
        int m = c >> 2, kc = c & 3;
        int kcs = kc ^ (m & 3);
        size_t ga;
        if (MODE == 0) {
          ga = (size_t)(row0 + m) * KK + kb * 32 + kcs * 8;
        } else {
          int r = row0 + m;
          int bb = r / TOUT_;
          int t = r - bb * TOUT_;
          int k = (kb * 32) >> 9;
          int ci = ((kb * 32) & 511) + kcs * 8;
          int gt = refl(t * SS - PP + k, TIN_);
          ga = (((size_t)(bb * TIN_ + gt)) << 9) + ci;
        }
        aP[rr] = (const char*)(A + ga);
      }
    }
#pragma unroll
    for (int rr = 0; rr < 2; rr++) {
      gld16((char*)&sA[buf][0] + (rr * 256 + tid) * 16, aP[rr]);
      aP[rr] += 64;
    }
  };

  // Stages a full 64-K chunk (2 sub-tiles) into chunk-buf `buf`; advances bP by 128B.
  auto stageB = [&](int buf, bool doSub1) {
#pragma unroll
    for (int rr = 0; rr < 2; rr++) {
      gld16((char*)&sB[buf][0][0] + (rr * 256 + tid) * 16, bP[rr]);
      if (doSub1) gld16((char*)&sB[buf][1][0] + (rr * 256 + tid) * 16, bP[rr] + 64);
      bP[rr] += 128;
    }
  };

#pragma unroll
  for (int rr = 0; rr < 2; rr++) {
    int c = rr * 256 + tid;
    int n = c >> 2, kc = c & 3;
    int kcs = kc ^ (n & 3);
    bP[rr] = (const char*)(Bt + (size_t)(col0 + n) * KK + kb0 * 32 + kcs * 8);
  }

  f32x4 acc[4][4];
  const f32x4 zz = {0.f, 0.f, 0.f, 0.f};
#pragma unroll
  for (int mi = 0; mi < 4; mi++)
#pragma unroll
    for (int ni = 0; ni < 4; ni++) acc[mi][ni] = zz;

  stageA(kb0, 0);
  stageB(0, kb0 + 1 < kb1);

  const int p = cq ^ (cl & 3);
  for (int kb = kb0; kb < kb1; kb++) {
    const int jj = kb - kb0;
    __syncthreads();
    if (kb + 1 < kb1) stageA(kb + 1, (jj + 1) & 1);
    if (((jj & 1) == 0) && (kb + 2 < kb1)) stageB(((jj >> 1) + 1) & 1, kb + 3 < kb1);
    const short* bA = (const short*)&sA[jj & 1][0];
    const short* bB = (const short*)&sB[(jj >> 1) & 1][jj & 1][0];
    bf16x8 af[4], bfr[4];
#pragma unroll
    for (int mi = 0; mi < 4; mi++)
      af[mi] = *(const bf16x8*)(bA + (wm * 64 + mi * 16 + cl) * 32 + p * 8);
#pragma unroll
    for (int ni = 0; ni < 4; ni++)
      bfr[ni] = *(const bf16x8*)(bB + (wn * 64 + ni * 16 + cl) * 32 + p * 8);
#pragma unroll
    for (int mi = 0; mi < 4; mi++)
#pragma unroll
      for (int ni = 0; ni < 4; ni++)
        acc[mi][ni] = __builtin_amdgcn_mfma_f32_16x16x32_bf16(af[mi], bfr[ni], acc[mi][ni], 0, 0, 0);
  }

#pragma unroll
  for (int mi = 0; mi < 4; mi++)
#pragma unroll
    for (int ni = 0; ni < 4; ni++)
#pragma unroll
      for (int r2 = 0; r2 < 4; r2++) {
        int row = row0 + wm * 64 + mi * 16 + cq * 4 + r2;
        int col = col0 + wn * 64 + ni * 16 + cl;
        Cp[(size_t)sk * MM * NN + (size_t)row * NN + col] = __float2bfloat16(acc[mi][ni][r2]);
      }
}

// ---------------- GEMM C: 64x128 tile (conv3, mlp1), A dbuf + B chunk-dbuf, 4 blocks/CU --
template <int MODE, int TIN_, int TOUT_, int SS, int PP, int KK, int NN, int EPI, int SPLITK, int MM>
__global__ __launch_bounds__(256, 4) void k_gemmC(const __hip_bfloat16* __restrict__ A,
                                                  const __hip_bfloat16* __restrict__ Bt,
                                                  const float* __restrict__ bias,
                                                  __hip_bfloat16* __restrict__ Cout) {
  __shared__ __align__(16) __hip_bfloat16 sA[2][64 * 32];
  __shared__ __align__(16) __hip_bfloat16 sB[2][2][128 * 32];  // [chunk-buf][sub][...]
  const int tid = threadIdx.x;
  const int lane = tid & 63;
  const int wave = tid >> 6;
  const int wm = wave >> 1, wn = wave & 1;
  constexpr int nt = NN / 128;
  constexpr int PS = (MM / 512) * nt;
  constexpr int KBT = KK / 32;
  const int blk = blockIdx.x;
  const int xs = blk & 7, sl = blk >> 3;
  const int sk = sl / PS, rem = sl % PS;
  const int row0 = ((rem / nt) * 8 + xs) * 64;
  const int col0 = (rem % nt) * 128;
  const int kb0 = (sk * KBT) / SPLITK, kb1 = ((sk + 1) * KBT) / SPLITK;
  const int cq = lane >> 4, cl = lane & 15;

  const char* aP;
  const char* bP[2];

  auto stageA = [&](int kb, int buf) {
    bool recalc = (kb == kb0) || (MODE == 1 && (kb & 15) == 0);
    if (recalc) {
      int m = tid >> 2, kc = tid & 3;
      int kcs = kc ^ (m & 3);
      size_t ga;
      if (MODE == 0) {
        ga = (size_t)(row0 + m) * KK + kb * 32 + kcs * 8;
      } else {
        int r = row0 + m;
        int bb = r / TOUT_;
        int t = r - bb * TOUT_;
        int k = (kb * 32) >> 9;
        int ci = ((kb * 32) & 511) + kcs * 8;
        int gt = refl(t * SS - PP + k, TIN_);
        ga = (((size_t)(bb * TIN_ + gt)) << 9) + ci;
      }
      aP = (const char*)(A + ga);
    }
    gld16((char*)&sA[buf][0] + tid * 16, aP);
    aP += 64;
  };

  auto stageB = [&](int buf, bool doSub1) {
#pragma unroll
    for (int rr = 0; rr < 2; rr++) {
      gld16((char*)&sB[buf][0][0] + (rr * 256 + tid) * 16, bP[rr]);
      if (doSub1) gld16((char*)&sB[buf][1][0] + (rr * 256 + tid) * 16, bP[rr] + 64);
      bP[rr] += 128;
    }
  };

#pragma unroll
  for (int rr = 0; rr < 2; rr++) {
    int c = rr * 256 + tid;
    int n = c >> 2, kc = c & 3;
    int kcs = kc ^ (n & 3);
    bP[rr] = (const char*)(Bt + (size_t)(col0 + n) * KK + kb0 * 32 + kcs * 8);
  }

  f32x4 acc[2][4];
  const f32x4 zz = {0.f, 0.f, 0.f, 0.f};
#pragma unroll
  for (int mi = 0; mi < 2; mi++)
#pragma unroll
    for (int ni = 0; ni < 4; ni++) acc[mi][ni] = zz;

  stageA(kb0, 0);
  stageB(0, kb0 + 1 < kb1);

  const int p = cq ^ (cl & 3);
  for (int kb = kb0; kb < kb1; kb++) {
    const int jj = kb - kb0;
    __syncthreads();
    if (kb + 1 < kb1) stageA(kb + 1, (jj + 1) & 1);
    if (((jj & 1) == 0) && (kb + 2 < kb1)) stageB(((jj >> 1) + 1) & 1, kb + 3 < kb1);
    const short* bA = (const short*)&sA[jj & 1][0];
    const short* bB = (const short*)&sB[(jj >> 1) & 1][jj & 1][0];
    bf16x8 af[2], bfr[4];
#pragma unroll
    for (int mi = 0; mi < 2; mi++)
      af[mi] = *(const bf16x8*)(bA + (wm * 32 + mi * 16 + cl) * 32 + p * 8);
#pragma unroll
    for (int ni = 0; ni < 4; ni++)
      bfr[ni] = *(const bf16x8*)(bB + (wn * 64 + ni * 16 + cl) * 32 + p * 8);
#pragma unroll
    for (int mi = 0; mi < 2; mi++)
#pragma unroll
      for (int ni = 0; ni < 4; ni++)
        acc[mi][ni] = __builtin_amdgcn_mfma_f32_16x16x32_bf16(af[mi], bfr[ni], acc[mi][ni], 0, 0, 0);
  }

#pragma unroll
  for (int mi = 0; mi < 2; mi++)
#pragma unroll
    for (int ni = 0; ni < 4; ni++)
#pragma unroll
      for (int r2 = 0; r2 < 4; r2++) {
        int row = row0 + wm * 32 + mi * 16 + cq * 4 + r2;
        int col = col0 + wn * 64 + ni * 16 + cl;
        float v = acc[mi][ni][r2];
        if (EPI == 1) {
          v += bias[col];
          v = 0.5f * v * (1.f + erff(v * 0.70710678118654752f));
          Cout[(size_t)row * NN + col] = __float2bfloat16(v);
        } else {
          Cout[(size_t)sk * MM * NN + (size_t)row * NN + col] = __float2bfloat16(v);
        }
      }
}

// ---------------- ChannelNorm (+conv bias, sum NS bf16 split-K partials) + ReLU -> bf16
template <int NS>
__global__ __launch_bounds__(512) void k_cnorm(const __hip_bfloat16* __restrict__ g,
                                               const float* __restrict__ cb,
                                               const float* __restrict__ gw, const float* __restrict__ gb,
                                               __hip_bfloat16* __restrict__ out, size_t stride) {
  int wave = threadIdx.x >> 6, lane = threadIdx.x & 63;
  size_t row = (size_t)blockIdx.x * 8 + wave;
  float v[8];
  {
    float4 c0 = *(const float4*)(cb + lane * 8), c1 = *(const float4*)(cb + lane * 8 + 4);
    v[0] = c0.x; v[1] = c0.y; v[2] = c0.z; v[3] = c0.w;
    v[4] = c1.x; v[5] = c1.y; v[6] = c1.z; v[7] = c1.w;
  }
#pragma unroll
  for (int s = 0; s < NS; s++) add_bf8(g + s * stride + row * NC + lane * 8, v);
  float s = 0.f, q = 0.f;
#pragma unroll
  for (int j = 0; j < 8; j++) { s += v[j]; q += v[j] * v[j]; }
#pragma unroll
  for (int off = 32; off > 0; off >>= 1) {
    s += __shfl_xor(s, off, 64);
    q += __shfl_xor(q, off, 64);
  }
  float mean = s * (1.f / NC);
  float var = fmaxf((q - s * s * (1.f / NC)) * (1.f / (NC - 1)), 0.f);
  float rstd = rsqrtf(var + EPSF);
  float4 w0 = *(const float4*)(gw + lane * 8), w1 = *(const float4*)(gw + lane * 8 + 4);
  float4 b0 = *(const float4*)(gb + lane * 8), b1 = *(const float4*)(gb + lane * 8 + 4);
  float gwv[8] = {w0.x, w0.y, w0.z, w0.w, w1.x, w1.y, w1.z, w1.w};
  float gbv[8] = {b0.x, b0.y, b0.z, b0.w, b1.x, b1.y, b1.z, b1.w};
  union { __hip_bfloat16 h[8]; uint4 u; } pk;
#pragma unroll
  for (int j = 0; j < 8; j++)
    pk.h[j] = __float2bfloat16(fmaxf((v[j] - mean) * rstd * gwv[j] + gbv[j], 0.f));
  *(uint4*)(out + row * NC + lane * 8) = pk.u;
}

// ---------------- fused head: sum NS bf16 partials + bias + GELU, dot w3, sigmoid ----
template <int NS>
__global__ __launch_bounds__(256) void k_head(const __hip_bfloat16* __restrict__ g,
                                              const float* __restrict__ b2,
                                              const float* __restrict__ w3, const float* __restrict__ b3,
                                              float* __restrict__ imp) {
  __shared__ float red[4];
  int row = blockIdx.x, tid = threadIdx.x;
  int c = tid * 8;
  float v[8];
  {
    float4 x0 = *(const float4*)(b2 + c), x1 = *(const float4*)(b2 + c + 4);
    v[0] = x0.x; v[1] = x0.y; v[2] = x0.z; v[3] = x0.w;
    v[4] = x1.x; v[5] = x1.y; v[6] = x1.z; v[7] = x1.w;
  }
#pragma unroll
  for (int s = 0; s < NS; s++) add_bf8(g + (size_t)s * (2048 * DM) + (size_t)row * DM + c, v);
  float a = 0.f;
  float4 w0 = *(const float4*)(w3 + c), w1 = *(const float4*)(w3 + c + 4);
  float wv[8] = {w0.x, w0.y, w0.z, w0.w, w1.x, w1.y, w1.z, w1.w};
#pragma unroll
  for (int j = 0; j < 8; j++) {
    float z = 0.5f * v[j] * (1.f + erff(v[j] * 0.70710678118654752f));
    a += z * wv[j];
  }
#pragma unroll
  for (int off = 32; off > 0; off >>= 1) a += __shfl_down(a, off, 64);
  int lane = tid & 63, wid = tid >> 6;
  if (lane == 0) red[wid] = a;
  __syncthreads();
  if (tid == 0) {
    float s = red[0] + red[1] + red[2] + red[3] + b3[0];
    imp[row] = 1.f / (1.f + expf(-s)) + TEMPF;
  }
}

__device__ __forceinline__ float dfun(float cv, int n) {
  float d = fmaxf(cv - (float)n, 0.f);
  if (n < TN - 1) d = fminf(d, 1.f);
  return d;
}

// ---------------- fused cumsum + pool + final ChannelNorm + ReLU, write [B][C][TN] ----
// R12 fix (−22us e2e): nonzero support of wt is a contiguous t-range (cumsum monotone),
// found via per-wave ballot + 8-entry min/max; loop only [tmin,tmax] (~2-4 iters vs 512
// serial ~120cy LDS broadcasts). if(w!=0) kept -> FP sum over nonzero terms unchanged.
__global__ __launch_bounds__(512) void k_poolfinal(const __hip_bfloat16* __restrict__ f,
                                                   const float* __restrict__ imp,
                                                   const float* __restrict__ gw, const float* __restrict__ gb,
                                                   float* __restrict__ out) {
  __shared__ float wt[T3];
  __shared__ float wsum[8];
  __shared__ float red[16];
  __shared__ int rmin[8], rmax[8];
  int b = blockIdx.x / TN, n = blockIdx.x % TN;
  int tid = threadIdx.x, wave = tid >> 6, lane = tid & 63;
  float own = imp[b * T3 + tid];
  float s = own;
#pragma unroll
  for (int off = 1; off < 64; off <<= 1) {
    float t = __shfl_up(s, off, 64);
    if (lane >= off) s += t;
  }
  if (lane == 63) wsum[wave] = s;
  __syncthreads();
  float prefix = 0.f, total = 0.f;
#pragma unroll
  for (int w = 0; w < 8; w++) {
    float ws_ = wsum[w];
    total += ws_;
    if (w < wave) prefix += ws_;
  }
  float scale = (float)TN / total;
  float incl = (prefix + s) * scale;
  float excl = (prefix + s - own) * scale;
  float myw = dfun(incl, n) - dfun(excl, n);
  wt[tid] = myw;
  // locate the contiguous nonzero t-range
  unsigned long long m = __ballot(myw != 0.f);
  if (lane == 0) {
    rmin[wave] = m ? (wave * 64 + __ffsll(m) - 1) : T3;
    rmax[wave] = m ? (wave * 64 + 63 - __clzll(m)) : -1;
  }
  __syncthreads();
  int tmin = T3, tmax = -1;
#pragma unroll
  for (int w = 0; w < 8; w++) {
    tmin = min(tmin, rmin[w]);
    tmax = max(tmax, rmax[w]);
  }
  float acc = 0.f;
  for (int t = tmin; t <= tmax; t++) {
    float w = wt[t];
    if (w != 0.f) acc += w * __bfloat162float(f[((size_t)b * T3 + t) * NC + tid]);
  }
  float sv = acc, q = acc * acc;
  blk_sum2_512(sv, q, red);
  float mean = sv * (1.f / NC);
  float var = fmaxf((q - sv * sv * (1.f / NC)) * (1.f / (NC - 1)), 0.f);
  float y = (acc - mean) * rsqrtf(var + EPSF) * gw[tid] + gb[tid];
  out[((size_t)b * NC + tid) * TN + n] = fmaxf(y, 0.f);
}

extern "C" void kernel_launch(void* const* d_in, const int* in_sizes, int n_in,
                              void* d_out, int out_size, void* d_ws, size_t ws_size,
                              hipStream_t stream) {
  const float* x   = (const float*)d_in[0];
  const float* c0w = (const float*)d_in[1];  const float* c0b = (const float*)d_in[2];
  const float* c1w = (const float*)d_in[3];  const float* c1b = (const float*)d_in[4];
  const float* c2w = (const float*)d_in[5];  const float* c2b = (const float*)d_in[6];
  const float* c3w = (const float*)d_in[7];  const float* c3b = (const float*)d_in[8];
  const float* mw1 = (const float*)d_in[9];  const float* mb1 = (const float*)d_in[10];
  const float* mw2 = (const float*)d_in[11]; const float* mb2 = (const float*)d_in[12];
  const float* mw3 = (const float*)d_in[13]; const float* mb3 = (const float*)d_in[14];
  const float* n0w = (const float*)d_in[15]; const float* n0b = (const float*)d_in[16];
  const float* n1w = (const float*)d_in[17]; const float* n1b = (const float*)d_in[18];
  const float* n2w = (const float*)d_in[19]; const float* n2b = (const float*)d_in[20];
  const float* n3w = (const float*)d_in[21]; const float* n3b = (const float*)d_in[22];
  const float* n4w = (const float*)d_in[23]; const float* n4b = (const float*)d_in[24];

  char* base = (char*)d_ws;
  // Workspace map (MiB). Peak 82 MiB (R8 layout).
  __hip_bfloat16* h0b  = (__hip_bfloat16*)(base);                     // [0,32): conv0 out; dead after conv1-gemm
  __hip_bfloat16* h1b  = (__hip_bfloat16*)(base);                     // reuse [0,8)
  __hip_bfloat16* h2b  = (__hip_bfloat16*)(base + (8u << 20));        // reuse [8,12)
  __hip_bfloat16* h3b  = (__hip_bfloat16*)(base + (12u << 20));       // reuse [12,14)
  __hip_bfloat16* z1b  = (__hip_bfloat16*)(base + (14u << 20));       // reuse [14,22)
  float*          imp  = (float*)(base + (22u << 20));                // reuse [22,+8K)
  __hip_bfloat16* g    = (__hip_bfloat16*)(base + (32u << 20));       // [32,64): bf16 split-K partials
  __hip_bfloat16* wm1t = (__hip_bfloat16*)(base + (64u << 20));       // [64,66)
  __hip_bfloat16* wt2  = (__hip_bfloat16*)(base + (66u << 20));       // [66,68)
  __hip_bfloat16* wt3  = (__hip_bfloat16*)(base + (68u << 20));       // [68,70)
  __hip_bfloat16* wt1  = (__hip_bfloat16*)(base + (70u << 20));       // [70,74)
  __hip_bfloat16* wm2t = (__hip_bfloat16*)(base + (74u << 20));       // [74,82)
  float* outp = (float*)d_out;

  k_init<<<4096 + 6656, 512, 0, stream>>>(x, c0w, c0b, n0w, n0b, h0b,
                                          c1w, c2w, c3w, mw1, mw2, wt1, wt2, wt3, wm1t, wm2t);

  // conv1: 256x256 ring-4 counted-vmcnt gemmF (measured 44.5-44.9us, 3 runs), SK4 -> 256 blocks.
  k_gemmF<1, 8192, 2048, 4, 2, 4096, 512, 4, 8192><<<256, 512, 0, stream>>>(h0b, wt1, g);
  k_cnorm<4><<<8192 / 8, 512, 0, stream>>>(g, c1b, n1w, n1b, h1b, (size_t)8192 * 512);
  // conv2: 128x128, SK6 -> 768 blocks (3/CU)
  k_gemmB<1, 2048, 1024, 2, 1, 2048, 512, 6, 4096><<<768, 256, 0, stream>>>(h1b, wt2, g);
  k_cnorm<6><<<4096 / 8, 512, 0, stream>>>(g, c2b, n2w, n2b, h2b, (size_t)4096 * 512);
  // conv3: 64x128, SK6 -> 768 blocks
  k_gemmC<1, 1024, 512, 2, 1, 2048, 512, 0, 6, 2048><<<768, 256, 0, stream>>>(h2b, wt3, c3b, g);
  k_cnorm<6><<<2048 / 8, 512, 0, stream>>>(g, c3b, n3w, n3b, h3b, (size_t)2048 * 512);
  // mlp1: 64x128, EPI=GELU -> 512 blocks
  k_gemmC<0, 0, 1, 0, 0, 512, 2048, 1, 1, 2048><<<512, 256, 0, stream>>>(h3b, wm1t, mb1, z1b);
  // mlp2: 128x128, SK3 -> 768 blocks (gemmF measured ~5us slower here; keep gemmB)
  k_gemmB<0, 0, 1, 0, 0, 2048, 2048, 3, 2048><<<768, 256, 0, stream>>>(z1b, wm2t, g);

  k_head<3><<<NB * T3, 256, 0, stream>>>(g, mb2, mw3, mb3, imp);
  k_poolfinal<<<NB * TN, 512, 0, stream>>>(h3b, imp, n4w, n4b, outp);
}